// Round 2
// baseline (2496.630 us; speedup 1.0000x reference)
//
#include <hip/hip_runtime.h>
#include <hip/hip_bf16.h>
#include <math.h>

// Problem constants (B=4, S=2048, IN=256, EMB=512, H=8, D=64)
#define BB   4
#define SS   2048
#define INF_ 256
#define EMB  512
#define NH   8
#define HD   64
#define NT   8192           // B*S tokens

typedef __hip_bfloat16 bf16;

constexpr float SCALE = 0.04419417382415922f;  // 1/sqrt(512)
constexpr float EPS   = 1e-5f;

// ---------------------------------------------------------------------------
// Runtime input-dtype detection. Interpret low half-word of each 32-bit word
// of state_emb as bf16: real bf16 data -> plausible exponents (~100%);
// fp32 data -> uniform mantissa bits (~12% plausible). flag=1 means fp32.
// ---------------------------------------------------------------------------
__global__ __launch_bounds__(256) void detect_dtype(
    const unsigned short* __restrict__ x, int* __restrict__ flag)
{
    __shared__ int cnt;
    if (threadIdx.x == 0) cnt = 0;
    __syncthreads();
    const unsigned short lo = x[threadIdx.x * 2];
    const unsigned e = (lo >> 7) & 0xFF;
    const int plausible = (e == 0 || (e >= 110 && e <= 140)) ? 1 : 0;
    atomicAdd(&cnt, plausible);
    __syncthreads();
    if (threadIdx.x == 0) *flag = (cnt < 128) ? 1 : 0;
}

// Convert any input tensor to canonical f32 per detected dtype.
__global__ __launch_bounds__(256) void convert_in(
    const void* __restrict__ src, float* __restrict__ dst, int n,
    const int* __restrict__ flag)
{
    const int i = blockIdx.x * 256 + threadIdx.x;
    if (i >= n) return;
    if (*flag) dst[i] = ((const float*)src)[i];
    else       dst[i] = __bfloat162float(((const bf16*)src)[i]);
}

// ---------------------------------------------------------------------------
// Tiled GEMM: C[N x M] = act(A[N x K] @ W[K x M] + bias), all f32.
// 64x64 tile, BK=16, 256 threads, 4x4 micro-tile per thread.
// ---------------------------------------------------------------------------
template <bool RELU>
__global__ __launch_bounds__(256) void gemm_bias(
    const float* __restrict__ A, const float* __restrict__ W,
    const float* __restrict__ bias, float* __restrict__ C,
    int N, int K, int M)
{
    __shared__ float As[64][17];
    __shared__ float Ws[16][64];

    const int tid = threadIdx.x;
    const int tx = tid & 15, ty = tid >> 4;
    const int row0 = blockIdx.y * 64, col0 = blockIdx.x * 64;

    float acc[4][4] = {};
    const int ntiles = K >> 4;

    for (int t = 0; t < ntiles; ++t) {
        const int k0 = t << 4;
        #pragma unroll
        for (int i = 0; i < 4; ++i) {
            int idx = tid + i * 256;
            int r = idx >> 4, c = idx & 15;
            As[r][c] = A[(size_t)(row0 + r) * K + k0 + c];
        }
        #pragma unroll
        for (int i = 0; i < 4; ++i) {
            int idx = tid + i * 256;
            int r = idx >> 6, c = idx & 63;
            Ws[r][c] = W[(size_t)(k0 + r) * M + col0 + c];
        }
        __syncthreads();
        #pragma unroll
        for (int kk = 0; kk < 16; ++kk) {
            float a[4], b[4];
            #pragma unroll
            for (int i = 0; i < 4; ++i) a[i] = As[ty * 4 + i][kk];
            #pragma unroll
            for (int j = 0; j < 4; ++j) b[j] = Ws[kk][tx * 4 + j];
            #pragma unroll
            for (int i = 0; i < 4; ++i)
                #pragma unroll
                for (int j = 0; j < 4; ++j)
                    acc[i][j] += a[i] * b[j];
        }
        __syncthreads();
    }

    #pragma unroll
    for (int i = 0; i < 4; ++i) {
        const int r = row0 + ty * 4 + i;
        #pragma unroll
        for (int j = 0; j < 4; ++j) {
            const int c = col0 + tx * 4 + j;
            float v = acc[i][j] + bias[c];
            if (RELU) v = fmaxf(v, 0.0f);
            C[(size_t)r * M + c] = v;
        }
    }
}

// ---------------------------------------------------------------------------
// Flash attention: one block per (64-query tile, head, batch). 256 threads:
// thread t -> query ql=t>>2, slot=t&3 (16 keys & 16 output dims per thread).
// LDS: Qs/Ks/Vs f32 + Ps bf16 = 58,368 B (< 64 KiB).
// ---------------------------------------------------------------------------
__global__ __launch_bounds__(256) void attention(
    const float* __restrict__ q, const float* __restrict__ k,
    const float* __restrict__ v, float* __restrict__ ctx)
{
    __shared__ float Qs[64][65];
    __shared__ float Ks[64][65];
    __shared__ float Vs[64][65];
    __shared__ bf16  Ps[64][66];

    const int tid = threadIdx.x;
    const int q0 = blockIdx.x * 64;
    const int h  = blockIdx.y;
    const int b  = blockIdx.z;
    const size_t base = (size_t)b * SS * EMB + (size_t)h * HD;

    #pragma unroll
    for (int i = 0; i < 16; ++i) {
        int idx = tid + i * 256;
        int r = idx >> 6, d = idx & 63;
        Qs[r][d] = q[base + (size_t)(q0 + r) * EMB + d];
    }

    const int ql = tid >> 2, slot = tid & 3;
    float m = -1e4f, l = 0.0f;
    float acc[16];
    #pragma unroll
    for (int i = 0; i < 16; ++i) acc[i] = 0.0f;

    for (int t = 0; t < SS / 64; ++t) {
        const int j0 = t * 64;
        __syncthreads();   // previous tile fully consumed (also covers Qs @ t=0)
        #pragma unroll
        for (int i = 0; i < 16; ++i) {
            int idx = tid + i * 256;
            int r = idx >> 6, d = idx & 63;
            Ks[r][d] = k[base + (size_t)(j0 + r) * EMB + d];
            Vs[r][d] = v[base + (size_t)(j0 + r) * EMB + d];
        }
        __syncthreads();

        float s[16];
        #pragma unroll
        for (int jj = 0; jj < 16; ++jj) {
            const int j = slot * 16 + jj;
            float dot = 0.0f;
            #pragma unroll
            for (int d = 0; d < 64; ++d) dot += Qs[ql][d] * Ks[j][d];
            s[jj] = dot * SCALE;
        }

        float tmax = s[0];
        #pragma unroll
        for (int jj = 1; jj < 16; ++jj) tmax = fmaxf(tmax, s[jj]);
        tmax = fmaxf(tmax, __shfl_xor(tmax, 1));
        tmax = fmaxf(tmax, __shfl_xor(tmax, 2));

        const float newm = fmaxf(m, tmax);
        const float alpha = expf(m - newm);
        float p[16], psum = 0.0f;
        #pragma unroll
        for (int jj = 0; jj < 16; ++jj) { p[jj] = expf(s[jj] - newm); psum += p[jj]; }
        psum += __shfl_xor(psum, 1);
        psum += __shfl_xor(psum, 2);
        l = l * alpha + psum;
        m = newm;
        #pragma unroll
        for (int i = 0; i < 16; ++i) acc[i] *= alpha;

        #pragma unroll
        for (int jj = 0; jj < 16; ++jj)
            Ps[ql][slot * 16 + jj] = __float2bfloat16(p[jj]);
        __syncthreads();

        for (int j = 0; j < 64; ++j) {
            const float pv = __bfloat162float(Ps[ql][j]);
            #pragma unroll
            for (int dd = 0; dd < 16; ++dd) acc[dd] += pv * Vs[j][slot * 16 + dd];
        }
    }

    const float inv = (l > 0.0f) ? (1.0f / l) : 0.0f;
    #pragma unroll
    for (int dd = 0; dd < 16; ++dd)
        ctx[base + (size_t)(q0 + ql) * EMB + slot * 16 + dd] = acc[dd] * inv;
}

// ---------------------------------------------------------------------------
// Fused residual + LayerNorm over EMB=512. One wave per row, 4 rows/block.
// FINAL=true writes d_out in the detected dtype (flag: 1=f32, 0=bf16).
// ---------------------------------------------------------------------------
template <bool FINAL>
__global__ __launch_bounds__(256) void layernorm_add(
    const float* __restrict__ a, const float* __restrict__ bres,
    const float* __restrict__ g, const float* __restrict__ beta,
    float* __restrict__ outf, void* __restrict__ dout,
    const int* __restrict__ flag)
{
    const int wave = threadIdx.x >> 6;
    const int lane = threadIdx.x & 63;
    const size_t row = (size_t)blockIdx.x * 4 + wave;
    const float* ar = a + row * EMB;
    const float* br = bres + row * EMB;

    float vals[8];
    float sum = 0.0f;
    #pragma unroll
    for (int i = 0; i < 8; ++i) {
        vals[i] = ar[lane + i * 64] + br[lane + i * 64];
        sum += vals[i];
    }
    #pragma unroll
    for (int o = 1; o < 64; o <<= 1) sum += __shfl_xor(sum, o);
    const float mu = sum * (1.0f / 512.0f);

    float vs = 0.0f;
    #pragma unroll
    for (int i = 0; i < 8; ++i) { float d = vals[i] - mu; vs += d * d; }
    #pragma unroll
    for (int o = 1; o < 64; o <<= 1) vs += __shfl_xor(vs, o);
    const float rstd = rsqrtf(vs * (1.0f / 512.0f) + EPS);

    const int isf32 = FINAL ? *flag : 0;
    #pragma unroll
    for (int i = 0; i < 8; ++i) {
        const int c = lane + i * 64;
        float y = (vals[i] - mu) * rstd * g[c] + beta[c];
        if (FINAL) {
            if (isf32) ((float*)dout)[row * EMB + c] = y;
            else       ((bf16*)dout)[row * EMB + c] = __float2bfloat16(y);
        } else {
            outf[row * EMB + c] = y;
        }
    }
}

// ---------------------------------------------------------------------------
extern "C" void kernel_launch(void* const* d_in, const int* in_sizes, int n_in,
                              void* d_out, int out_size, void* d_ws, size_t ws_size,
                              hipStream_t stream)
{
    float* ws = (float*)d_ws;
    size_t off = 0;

    // f32-converted copies of all 21 inputs
    float* cvt[21];
    for (int i = 0; i < 21; ++i) { cvt[i] = ws + off; off += (size_t)in_sizes[i]; }

    const size_t SZ = (size_t)NT * EMB;          // 4,194,304 floats
    float* q    = ws + off; off += SZ;
    float* kbuf = ws + off; off += SZ;
    float* vbuf = ws + off; off += SZ;
    float* h    = ws + off; off += 2 * SZ;       // [NT,1024]
    float* ctx  = ws + off; off += SZ;
    float* x1   = ws + off; off += SZ;
    int*   flag = (int*)(ws + off);              // ~135 MB total ws use

    // Detect input dtype, then convert all inputs to f32.
    detect_dtype<<<1, 256, 0, stream>>>((const unsigned short*)d_in[0], flag);
    for (int i = 0; i < 21; ++i) {
        const int n = in_sizes[i];
        convert_in<<<(n + 255) / 256, 256, 0, stream>>>(d_in[i], cvt[i], n, flag);
    }

    const float* x   = cvt[0];
    const float* qW1 = cvt[1],  *qb1 = cvt[2],  *qW2 = cvt[3],  *qb2 = cvt[4];
    const float* kW1 = cvt[5],  *kb1 = cvt[6],  *kW2 = cvt[7],  *kb2 = cvt[8];
    const float* vW1 = cvt[9],  *vb1 = cvt[10], *vW2 = cvt[11], *vb2 = cvt[12];
    const float* fW1 = cvt[13], *fb1 = cvt[14], *fW2 = cvt[15], *fb2 = cvt[16];
    const float* g1  = cvt[17], *be1 = cvt[18], *g2  = cvt[19], *be2 = cvt[20];

    const dim3 blk(256);
    const dim3 g512(EMB / 64, NT / 64);          // (8,128)
    const dim3 g1024(1024 / 64, NT / 64);        // (16,128)

    // Q/K/V projections: h = relu(x@W1+b1); out = h@W2+b2
    gemm_bias<true ><<<g512, blk, 0, stream>>>(x, qW1, qb1, h, NT, INF_, EMB);
    gemm_bias<false><<<g512, blk, 0, stream>>>(h, qW2, qb2, q, NT, EMB, EMB);
    gemm_bias<true ><<<g512, blk, 0, stream>>>(x, kW1, kb1, h, NT, INF_, EMB);
    gemm_bias<false><<<g512, blk, 0, stream>>>(h, kW2, kb2, kbuf, NT, EMB, EMB);
    gemm_bias<true ><<<g512, blk, 0, stream>>>(x, vW1, vb1, h, NT, INF_, EMB);
    gemm_bias<false><<<g512, blk, 0, stream>>>(h, vW2, vb2, vbuf, NT, EMB, EMB);

    // Attention
    attention<<<dim3(SS / 64, NH, BB), blk, 0, stream>>>(q, kbuf, vbuf, ctx);

    // x1 = LN(ctx + q)
    layernorm_add<false><<<NT / 4, blk, 0, stream>>>(ctx, q, g1, be1, x1, nullptr, flag);

    // FFN: h = relu(x1@fW1+fb1) [NT,1024]; y = h@fW2+fb2 -> reuse ctx
    gemm_bias<true ><<<g1024, blk, 0, stream>>>(x1, fW1, fb1, h, NT, EMB, 1024);
    gemm_bias<false><<<g512, blk, 0, stream>>>(h, fW2, fb2, ctx, NT, 1024, EMB);

    // out = LN(x1 + y) in detected dtype
    layernorm_add<true><<<NT / 4, blk, 0, stream>>>(x1, ctx, g2, be2, nullptr, d_out, flag);
}

// Round 3
// 306.666 us; speedup vs baseline: 8.1412x; 8.1412x over previous
//
#include <hip/hip_runtime.h>
#include <hip/hip_bf16.h>
#include <math.h>

#define BB   4
#define SS   2048
#define INF_ 256
#define EMB  512
#define NH   8
#define HD   64
#define NT   8192

typedef unsigned short u16;
typedef __attribute__((ext_vector_type(8))) short bf16x8;   // 8 bf16 = 4 VGPRs
typedef __attribute__((ext_vector_type(4))) float f32x4;

constexpr float SCALE = 0.04419417382415922f;  // 1/sqrt(512)
constexpr float EPS   = 1e-5f;

__device__ __forceinline__ u16 f2bf(float v) {
    __hip_bfloat16 h = __float2bfloat16(v);
    return *(u16*)&h;
}
__device__ __forceinline__ float bf2f(u16 u) {
    __hip_bfloat16 h = *(__hip_bfloat16*)&u;
    return __bfloat162float(h);
}

// async global->LDS, 16B per lane (guide §5, m97 idiom)
__device__ __forceinline__ void async16(const void* g, void* l) {
    __builtin_amdgcn_global_load_lds(
        (const __attribute__((address_space(1))) void*)g,
        (__attribute__((address_space(3))) void*)l, 16, 0, 0);
}

// ---------------------------------------------------------------------------
// dtype detect (worked in round 1): flag=1 -> fp32 inputs, 0 -> bf16
// ---------------------------------------------------------------------------
__global__ __launch_bounds__(256) void detect_dtype(
    const u16* __restrict__ x, int* __restrict__ flag)
{
    __shared__ int cnt;
    if (threadIdx.x == 0) cnt = 0;
    __syncthreads();
    const u16 lo = x[threadIdx.x * 2];
    const unsigned e = (lo >> 7) & 0xFF;
    const int plausible = (e == 0 || (e >= 110 && e <= 140)) ? 1 : 0;
    atomicAdd(&cnt, plausible);
    __syncthreads();
    if (threadIdx.x == 0) *flag = (cnt < 128) ? 1 : 0;
}

// state_emb -> canonical bf16
__global__ __launch_bounds__(256) void conv_x(
    const void* __restrict__ src, u16* __restrict__ dst, int n,
    const int* __restrict__ flag)
{
    const int i = blockIdx.x * 256 + threadIdx.x;
    if (i >= n) return;
    dst[i] = (*flag) ? f2bf(((const float*)src)[i]) : ((const u16*)src)[i];
}

// 12 small vectors (biases + ln params) -> f32 packed buffer
__global__ __launch_bounds__(256) void conv_small(
    const void* s0, const void* s1, const void* s2, const void* s3,
    const void* s4, const void* s5, const void* s6, const void* s7,
    const void* s8, const void* s9, const void* s10, const void* s11,
    float* __restrict__ dst, const int* __restrict__ flag)
{
    // order: qb1,qb2,kb1,kb2,vb1,vb2,fb1,fb2,g1,be1,g2,be2
    const int nn[12]  = {512,512,512,512,512,512,1024,512,512,512,512,512};
    const int off[12] = {0,1536,512,2048,1024,2560,3072,4096,4608,5120,5632,6144};
    const int id = blockIdx.y;
    const int i = blockIdx.x * 256 + threadIdx.x;
    if (i >= nn[id]) return;
    const void* src;
    switch (id) {
        case 0: src = s0; break;  case 1: src = s1; break;
        case 2: src = s2; break;  case 3: src = s3; break;
        case 4: src = s4; break;  case 5: src = s5; break;
        case 6: src = s6; break;  case 7: src = s7; break;
        case 8: src = s8; break;  case 9: src = s9; break;
        case 10: src = s10; break; default: src = s11; break;
    }
    dst[off[id] + i] = (*flag) ? ((const float*)src)[i] : bf2f(((const u16*)src)[i]);
}

// ---------------------------------------------------------------------------
// Weight transposes: W[K][M] -> Wt[M][K] bf16 (8 weights fused via blockIdx.z)
// ---------------------------------------------------------------------------
__global__ __launch_bounds__(256) void transpose_w8(
    const void* w0, const void* w1, const void* w2, const void* w3,
    const void* w4, const void* w5, const void* w6, const void* w7,
    u16* __restrict__ wt1, u16* __restrict__ wt2,
    u16* __restrict__ f1t, u16* __restrict__ f2t,
    const int* __restrict__ flag)
{
    const int z = blockIdx.z;
    int K, M; const void* src; u16* dst;
    switch (z) {
        case 0: K=256;  M=512;  src=w0; dst=wt1;               break; // qW1
        case 1: K=256;  M=512;  src=w1; dst=wt1 + 512*256;     break; // kW1
        case 2: K=256;  M=512;  src=w2; dst=wt1 + 2*512*256;   break; // vW1
        case 3: K=512;  M=512;  src=w3; dst=wt2;               break; // qW2
        case 4: K=512;  M=512;  src=w4; dst=wt2 + 512*512;     break; // kW2
        case 5: K=512;  M=512;  src=w5; dst=wt2 + 2*512*512;   break; // vW2
        case 6: K=512;  M=1024; src=w6; dst=f1t;               break; // fW1
        default: K=1024; M=512; src=w7; dst=f2t;               break; // fW2
    }
    const int m0 = blockIdx.x * 32, k0 = blockIdx.y * 32;
    if (m0 >= M || k0 >= K) return;
    __shared__ u16 t[32][33];
    const int tid = threadIdx.x, tx = tid & 31, ty = tid >> 5;
    const int isf = *flag;
    #pragma unroll
    for (int i = 0; i < 4; ++i) {
        const int kk = k0 + ty + i * 8;
        t[ty + i * 8][tx] = isf ? f2bf(((const float*)src)[(size_t)kk * M + m0 + tx])
                                : ((const u16*)src)[(size_t)kk * M + m0 + tx];
    }
    __syncthreads();
    #pragma unroll
    for (int i = 0; i < 4; ++i) {
        const int mm = m0 + ty + i * 8;
        dst[(size_t)mm * K + k0 + tx] = t[tx][ty + i * 8];
    }
}

// v bf16 [B*S][EMB] -> Vt bf16 [B][H][HD][S]
__global__ __launch_bounds__(256) void transpose_v(
    const u16* __restrict__ v, u16* __restrict__ vt)
{
    __shared__ u16 t[32][33];
    const int tid = threadIdx.x, tx = tid & 31, ty = tid >> 5;
    const int s0 = blockIdx.x * 32, d0 = blockIdx.y * 32;
    const int bh = blockIdx.z, b = bh >> 3, h = bh & 7;
    #pragma unroll
    for (int i = 0; i < 4; ++i) {
        const int s = s0 + ty + i * 8;
        t[ty + i * 8][tx] = v[((size_t)b * SS + s) * EMB + h * HD + d0 + tx];
    }
    __syncthreads();
    #pragma unroll
    for (int i = 0; i < 4; ++i) {
        const int d = d0 + ty + i * 8;
        vt[((size_t)bh * HD + d) * SS + s0 + tx] = t[tx][ty + i * 8];
    }
}

// ---------------------------------------------------------------------------
// MFMA GEMM (m97 structure): C[N,M] = act(A[N,K] @ Wt[M,K]^T + bias)
// 128x128 tile, BK=32, 4 waves (2x2 of 64x64), XOR-swizzled LDS,
// global_load_lds width=16. Optional which-indexed multi-matmul fusion.
// ---------------------------------------------------------------------------
template <bool RELU, bool AWHICH>
__global__ __launch_bounds__(256) void gemm_bt(
    const u16* __restrict__ Aall, const u16* __restrict__ Wtall,
    const float* __restrict__ ball, u16* __restrict__ outb,
    float* __restrict__ outf, int N, int K, int M)
{
    __shared__ __align__(16) u16 sA[128 * 32];
    __shared__ __align__(16) u16 sB[128 * 32];

    const int mtiles = M >> 7;
    const int which = blockIdx.x / mtiles;
    const int colb  = blockIdx.x % mtiles;
    const int row0 = blockIdx.y << 7, col0 = colb << 7;
    const u16* A  = Aall + (AWHICH ? (size_t)which * N * K : 0);
    const u16* Wt = Wtall + (size_t)which * M * K;
    const float* bias = ball + (size_t)which * M;

    const int tid = threadIdx.x;
    const int lane = tid & 63, w = tid >> 6;
    const int wrow = (w & 1) << 6, wcol = (w >> 1) << 6;
    const int c = lane & 15, quad = lane >> 4;

    f32x4 acc[4][4] = {};

    for (int k0 = 0; k0 < K; k0 += 32) {
        __syncthreads();
        #pragma unroll
        for (int i = 0; i < 2; ++i) {
            const int raw = i * 256 + tid;
            const int r = raw >> 2, swz = raw & 3;
            const int ch = swz ^ (r & 3);
            async16(A + (size_t)(row0 + r) * K + k0 + ch * 8, (char*)sA + raw * 16);
        }
        #pragma unroll
        for (int i = 0; i < 2; ++i) {
            const int raw = i * 256 + tid;
            const int r = raw >> 2, swz = raw & 3;
            const int ch = swz ^ (r & 3);
            async16(Wt + (size_t)(col0 + r) * K + k0 + ch * 8, (char*)sB + raw * 16);
        }
        __syncthreads();

        bf16x8 af[4], bfr[4];
        #pragma unroll
        for (int rt = 0; rt < 4; ++rt) {
            const int r = wrow + rt * 16 + c;
            af[rt] = *(const bf16x8*)&sA[(r * 4 + (quad ^ (r & 3))) * 8];
        }
        #pragma unroll
        for (int ct = 0; ct < 4; ++ct) {
            const int r = wcol + ct * 16 + c;
            bfr[ct] = *(const bf16x8*)&sB[(r * 4 + (quad ^ (r & 3))) * 8];
        }
        #pragma unroll
        for (int rt = 0; rt < 4; ++rt)
            #pragma unroll
            for (int ct = 0; ct < 4; ++ct)
                acc[rt][ct] = __builtin_amdgcn_mfma_f32_16x16x32_bf16(
                    af[rt], bfr[ct], acc[rt][ct], 0, 0, 0);
    }

    const size_t outW = (size_t)which * N * M;
    #pragma unroll
    for (int rt = 0; rt < 4; ++rt) {
        #pragma unroll
        for (int i = 0; i < 4; ++i) {
            const int row = row0 + wrow + rt * 16 + quad * 4 + i;
            #pragma unroll
            for (int ct = 0; ct < 4; ++ct) {
                const int col = col0 + wcol + ct * 16 + c;
                float v = acc[rt][ct][i] + bias[col];
                if (RELU) v = fmaxf(v, 0.0f);
                const size_t idx = (size_t)row * M + col;
                if (outb) outb[outW + idx] = f2bf(v);
                if (outf && which == 0) outf[idx] = v;
            }
        }
    }
}

// ---------------------------------------------------------------------------
// MFMA flash attention. Block = 4 waves, 64 queries (16/wave), per (b,h).
// S^T = K @ Q^T (per-lane softmax state for q = lane%16), P^T round-trips
// through per-wave swizzled LDS into A-layout, PV uses pre-transposed V.
// ---------------------------------------------------------------------------
__global__ __launch_bounds__(256) void attn_mfma(
    const u16* __restrict__ q, const u16* __restrict__ k,
    const u16* __restrict__ vt, float* __restrict__ ctx)
{
    __shared__ __align__(16) u16 sK[64 * 64];
    __shared__ __align__(16) u16 sV[64 * 64];
    __shared__ __align__(16) u16 sP[4][16 * 64];

    const int tid = threadIdx.x;
    const int w = tid >> 6, lane = tid & 63;
    const int c = lane & 15, quad = lane >> 4;
    const int q0 = blockIdx.x * 64;
    const int h = blockIdx.y, b = blockIdx.z;
    const size_t tokbase = (size_t)b * SS;
    const int hoff = h * HD;
    const size_t vtbase = (size_t)(b * NH + h) * HD * SS;

    // Q B-fragments in registers (2 K-chunks of 32)
    const int myq = q0 + w * 16 + c;
    bf16x8 qf[2];
    #pragma unroll
    for (int kt = 0; kt < 2; ++kt)
        qf[kt] = *(const bf16x8*)&q[(tokbase + myq) * EMB + hoff + kt * 32 + quad * 8];

    float m = -1e30f, l = 0.0f;
    f32x4 accO[4] = {};

    for (int t = 0; t < SS / 64; ++t) {
        const int j0 = t * 64;
        __syncthreads();
        #pragma unroll
        for (int i = 0; i < 2; ++i) {
            const int raw = i * 256 + tid;
            const int key = raw >> 3, swz = raw & 7;
            const int ch = swz ^ (key & 7);
            async16(&k[(tokbase + j0 + key) * EMB + hoff + ch * 8], (char*)sK + raw * 16);
        }
        #pragma unroll
        for (int i = 0; i < 2; ++i) {
            const int raw = i * 256 + tid;
            const int d = raw >> 3, swz = raw & 7;
            const int ch = swz ^ (d & 7);
            async16(&vt[vtbase + (size_t)d * SS + j0 + ch * 8], (char*)sV + raw * 16);
        }
        __syncthreads();

        // S^T[key][q]: A = K-tile, B = Q^T
        f32x4 accS[4] = {};
        #pragma unroll
        for (int mt = 0; mt < 4; ++mt) {
            const int key = mt * 16 + c;
            #pragma unroll
            for (int kt = 0; kt < 2; ++kt) {
                bf16x8 kf = *(const bf16x8*)&sK[(key * 8 + ((quad + 4 * kt) ^ (key & 7))) * 8];
                accS[mt] = __builtin_amdgcn_mfma_f32_16x16x32_bf16(kf, qf[kt], accS[mt], 0, 0, 0);
            }
        }

        // online softmax for q = c (keys split across quads)
        float s[16];
        float tmax = -1e30f;
        #pragma unroll
        for (int mt = 0; mt < 4; ++mt)
            #pragma unroll
            for (int i = 0; i < 4; ++i) {
                const float x = accS[mt][i] * SCALE;
                s[mt * 4 + i] = x;
                tmax = fmaxf(tmax, x);
            }
        tmax = fmaxf(tmax, __shfl_xor(tmax, 16));
        tmax = fmaxf(tmax, __shfl_xor(tmax, 32));
        const float mn = fmaxf(m, tmax);
        const float alpha = __expf(m - mn);
        float psum = 0.0f;
        u16 ph[16];
        #pragma unroll
        for (int ii = 0; ii < 16; ++ii) {
            const float p = __expf(s[ii] - mn);
            psum += p;
            ph[ii] = f2bf(p);
        }
        psum += __shfl_xor(psum, 16);
        psum += __shfl_xor(psum, 32);
        l = l * alpha + psum;
        m = mn;

        // write P^T -> sP[w][q=c][key], swizzled blocks of 8 halves
        #pragma unroll
        for (int mt = 0; mt < 4; ++mt) {
            const int chunkW = (quad >> 1) + 2 * mt;
            const int blk = c * 8 + (chunkW ^ (c & 7));
            uint2 pw;
            pw.x = (unsigned)ph[mt * 4] | ((unsigned)ph[mt * 4 + 1] << 16);
            pw.y = (unsigned)ph[mt * 4 + 2] | ((unsigned)ph[mt * 4 + 3] << 16);
            *(uint2*)((char*)&sP[w][0] + blk * 16 + 8 * (quad & 1)) = pw;
        }

        // rescale O rows (row q = quad*4+i lives on lane c=quad*4+i)
        float al[4];
        #pragma unroll
        for (int i = 0; i < 4; ++i) al[i] = __shfl(alpha, quad * 4 + i, 16);
        #pragma unroll
        for (int nt = 0; nt < 4; ++nt)
            #pragma unroll
            for (int i = 0; i < 4; ++i) accO[nt][i] *= al[i];

        // PV: A = P (LDS round trip), B = V via Vt tile
        bf16x8 pf[2];
        #pragma unroll
        for (int kt = 0; kt < 2; ++kt)
            pf[kt] = *(const bf16x8*)&sP[w][(c * 8 + ((quad + 4 * kt) ^ (c & 7))) * 8];
        #pragma unroll
        for (int nt = 0; nt < 4; ++nt) {
            const int d = nt * 16 + c;
            #pragma unroll
            for (int kt = 0; kt < 2; ++kt) {
                bf16x8 vf = *(const bf16x8*)&sV[(d * 8 + ((quad + 4 * kt) ^ (d & 7))) * 8];
                accO[nt] = __builtin_amdgcn_mfma_f32_16x16x32_bf16(pf[kt], vf, accO[nt], 0, 0, 0);
            }
        }
    }

    float li[4];
    #pragma unroll
    for (int i = 0; i < 4; ++i) {
        const float lv = __shfl(l, quad * 4 + i, 16);
        li[i] = (lv > 0.0f) ? (1.0f / lv) : 0.0f;
    }
    #pragma unroll
    for (int nt = 0; nt < 4; ++nt)
        #pragma unroll
        for (int i = 0; i < 4; ++i) {
            const int tok = q0 + w * 16 + quad * 4 + i;
            ctx[(tokbase + tok) * EMB + hoff + nt * 16 + c] = accO[nt][i] * li[i];
        }
}

// ---------------------------------------------------------------------------
// Residual + LayerNorm, one wave per row. ln_dual: f32 + bf16 outs.
// ---------------------------------------------------------------------------
__global__ __launch_bounds__(256) void ln_dual(
    const float* __restrict__ a, const float* __restrict__ b2,
    const float* __restrict__ g, const float* __restrict__ be,
    float* __restrict__ outf, u16* __restrict__ outb)
{
    const int wave = threadIdx.x >> 6, lane = threadIdx.x & 63;
    const size_t row = (size_t)blockIdx.x * 4 + wave;
    const float* ar = a + row * EMB;
    const float* br = b2 + row * EMB;
    float vals[8], sum = 0.0f;
    #pragma unroll
    for (int i = 0; i < 8; ++i) { vals[i] = ar[lane + i * 64] + br[lane + i * 64]; sum += vals[i]; }
    #pragma unroll
    for (int o = 1; o < 64; o <<= 1) sum += __shfl_xor(sum, o);
    const float mu = sum * (1.0f / 512.0f);
    float vs = 0.0f;
    #pragma unroll
    for (int i = 0; i < 8; ++i) { const float d = vals[i] - mu; vs += d * d; }
    #pragma unroll
    for (int o = 1; o < 64; o <<= 1) vs += __shfl_xor(vs, o);
    const float rstd = rsqrtf(vs * (1.0f / 512.0f) + EPS);
    #pragma unroll
    for (int i = 0; i < 8; ++i) {
        const int col = lane + i * 64;
        const float y = (vals[i] - mu) * rstd * g[col] + be[col];
        outf[row * EMB + col] = y;
        outb[row * EMB + col] = f2bf(y);
    }
}

__global__ __launch_bounds__(256) void ln_final(
    const float* __restrict__ a, const float* __restrict__ b2,
    const float* __restrict__ g, const float* __restrict__ be,
    void* __restrict__ dout, const int* __restrict__ flag)
{
    const int wave = threadIdx.x >> 6, lane = threadIdx.x & 63;
    const size_t row = (size_t)blockIdx.x * 4 + wave;
    const float* ar = a + row * EMB;
    const float* br = b2 + row * EMB;
    float vals[8], sum = 0.0f;
    #pragma unroll
    for (int i = 0; i < 8; ++i) { vals[i] = ar[lane + i * 64] + br[lane + i * 64]; sum += vals[i]; }
    #pragma unroll
    for (int o = 1; o < 64; o <<= 1) sum += __shfl_xor(sum, o);
    const float mu = sum * (1.0f / 512.0f);
    float vs = 0.0f;
    #pragma unroll
    for (int i = 0; i < 8; ++i) { const float d = vals[i] - mu; vs += d * d; }
    #pragma unroll
    for (int o = 1; o < 64; o <<= 1) vs += __shfl_xor(vs, o);
    const float rstd = rsqrtf(vs * (1.0f / 512.0f) + EPS);
    const int isf = *flag;
    #pragma unroll
    for (int i = 0; i < 8; ++i) {
        const int col = lane + i * 64;
        const float y = (vals[i] - mu) * rstd * g[col] + be[col];
        if (isf) ((float*)dout)[row * EMB + col] = y;
        else     ((u16*)dout)[row * EMB + col] = f2bf(y);
    }
}

// ---------------------------------------------------------------------------
extern "C" void kernel_launch(void* const* d_in, const int* in_sizes, int n_in,
                              void* d_out, int out_size, void* d_ws, size_t ws_size,
                              hipStream_t stream)
{
    char* ws = (char*)d_ws;
    int*   flag  = (int*)(ws + 0);
    float* small = (float*)(ws + 256);
    u16*   wt1   = (u16*)(ws + 32768);
    u16*   wt2   = (u16*)(ws + 819200);
    u16*   f1t   = (u16*)(ws + 2392064);
    u16*   f2t   = (u16*)(ws + 3440640);
    u16*   xbf   = (u16*)(ws + 4489216);
    u16*   h3    = (u16*)(ws + 8683520);    // [3][NT][512]; reused as h2 [NT][1024]
    u16*   qkv   = (u16*)(ws + 33849344);   // [3][NT][512] = q_bf | k_bf | v_bf
    u16*   vtb   = (u16*)(ws + 59015168);   // [B][H][64][S]
    float* qf32  = (float*)(ws + 67403776); // [NT][512]; reused as ff
    float* ctx   = (float*)(ws + 84180992);
    float* x1    = (float*)(ws + 100958208);
    u16*   x1b   = (u16*)(ws + 117735424);

    const dim3 blk(256);

    detect_dtype<<<1, blk, 0, stream>>>((const u16*)d_in[0], flag);
    conv_x<<<(NT * INF_ + 255) / 256, blk, 0, stream>>>(d_in[0], xbf, NT * INF_, flag);
    transpose_w8<<<dim3(32, 32, 8), blk, 0, stream>>>(
        d_in[1], d_in[5], d_in[9], d_in[3], d_in[7], d_in[11], d_in[13], d_in[15],
        wt1, wt2, f1t, f2t, flag);
    conv_small<<<dim3(4, 12), blk, 0, stream>>>(
        d_in[2], d_in[4], d_in[6], d_in[8], d_in[10], d_in[12],
        d_in[14], d_in[16], d_in[17], d_in[18], d_in[19], d_in[20], small, flag);

    // qkv layer 1: h3[which] = relu(x @ W1 + b1)
    gemm_bt<true, false><<<dim3(12, 64), blk, 0, stream>>>(
        xbf, wt1, small + 0, h3, nullptr, NT, INF_, EMB);
    // qkv layer 2: qkv[which] = h3[which] @ W2 + b2 (+ q also in f32)
    gemm_bt<false, true><<<dim3(12, 64), blk, 0, stream>>>(
        h3, wt2, small + 1536, qkv, qf32, NT, EMB, EMB);

    transpose_v<<<dim3(64, 2, 32), blk, 0, stream>>>(qkv + 2 * (size_t)NT * EMB, vtb);

    attn_mfma<<<dim3(SS / 64, NH, BB), blk, 0, stream>>>(
        qkv, qkv + (size_t)NT * EMB, vtb, ctx);

    // x1 = LN(ctx + q)
    ln_dual<<<NT / 4, blk, 0, stream>>>(ctx, qf32, small + 4608, small + 5120, x1, x1b);

    // FFN
    u16* h2 = h3;
    float* ff = qf32;
    gemm_bt<true, false><<<dim3(8, 64), blk, 0, stream>>>(
        x1b, f1t, small + 3072, h2, nullptr, NT, EMB, 1024);
    gemm_bt<false, false><<<dim3(4, 64), blk, 0, stream>>>(
        h2, f2t, small + 4096, nullptr, ff, NT, 1024, EMB);

    // out = LN(x1 + ff)
    ln_final<<<NT / 4, blk, 0, stream>>>(x1, ff, small + 5632, small + 6144, d_out, flag);
}

// Round 4
// 292.085 us; speedup vs baseline: 8.5476x; 1.0499x over previous
//
#include <hip/hip_runtime.h>
#include <hip/hip_bf16.h>
#include <math.h>

#define BB   4
#define SS   2048
#define INF_ 256
#define EMB  512
#define NH   8
#define HD   64
#define NT   8192

typedef unsigned short u16;
typedef __attribute__((ext_vector_type(8))) short bf16x8;   // 8 bf16 = 4 VGPRs
typedef __attribute__((ext_vector_type(8))) unsigned short u16x8;
typedef __attribute__((ext_vector_type(4))) float f32x4;

constexpr float SCALE = 0.04419417382415922f;    // 1/sqrt(512)
constexpr float C2    = 0.06375871607f;          // SCALE * log2(e)
constexpr float EPS   = 1e-5f;

__device__ __forceinline__ u16 f2bf(float v) {
    __hip_bfloat16 h = __float2bfloat16(v);
    return *(u16*)&h;
}
__device__ __forceinline__ float bf2f(u16 u) {
    __hip_bfloat16 h = *(__hip_bfloat16*)&u;
    return __bfloat162float(h);
}

// async global->LDS, 16B per lane (guide §5, m97 idiom)
__device__ __forceinline__ void async16(const void* g, void* l) {
    __builtin_amdgcn_global_load_lds(
        (const __attribute__((address_space(1))) void*)g,
        (__attribute__((address_space(3))) void*)l, 16, 0, 0);
}

// ---------------------------------------------------------------------------
// dtype detect: flag=1 -> fp32 inputs, 0 -> bf16
// ---------------------------------------------------------------------------
__global__ __launch_bounds__(256) void detect_dtype(
    const u16* __restrict__ x, int* __restrict__ flag)
{
    __shared__ int cnt;
    if (threadIdx.x == 0) cnt = 0;
    __syncthreads();
    const u16 lo = x[threadIdx.x * 2];
    const unsigned e = (lo >> 7) & 0xFF;
    const int plausible = (e == 0 || (e >= 110 && e <= 140)) ? 1 : 0;
    atomicAdd(&cnt, plausible);
    __syncthreads();
    if (threadIdx.x == 0) *flag = (cnt < 128) ? 1 : 0;
}

__global__ __launch_bounds__(256) void conv_x(
    const void* __restrict__ src, u16* __restrict__ dst, int n,
    const int* __restrict__ flag)
{
    const int i = blockIdx.x * 256 + threadIdx.x;
    if (i >= n) return;
    dst[i] = (*flag) ? f2bf(((const float*)src)[i]) : ((const u16*)src)[i];
}

// 12 small vectors (biases + ln params) -> f32 packed buffer
__global__ __launch_bounds__(256) void conv_small(
    const void* s0, const void* s1, const void* s2, const void* s3,
    const void* s4, const void* s5, const void* s6, const void* s7,
    const void* s8, const void* s9, const void* s10, const void* s11,
    float* __restrict__ dst, const int* __restrict__ flag)
{
    // order: qb1,qb2,kb1,kb2,vb1,vb2,fb1,fb2,g1,be1,g2,be2
    const int nn[12]  = {512,512,512,512,512,512,1024,512,512,512,512,512};
    const int off[12] = {0,1536,512,2048,1024,2560,3072,4096,4608,5120,5632,6144};
    const int id = blockIdx.y;
    const int i = blockIdx.x * 256 + threadIdx.x;
    if (i >= nn[id]) return;
    const void* src;
    switch (id) {
        case 0: src = s0; break;  case 1: src = s1; break;
        case 2: src = s2; break;  case 3: src = s3; break;
        case 4: src = s4; break;  case 5: src = s5; break;
        case 6: src = s6; break;  case 7: src = s7; break;
        case 8: src = s8; break;  case 9: src = s9; break;
        case 10: src = s10; break; default: src = s11; break;
    }
    dst[off[id] + i] = (*flag) ? ((const float*)src)[i] : bf2f(((const u16*)src)[i]);
}

// ---------------------------------------------------------------------------
// Weight transposes: W[K][M] -> Wt[M][K] bf16 (8 weights via blockIdx.z)
// ---------------------------------------------------------------------------
__global__ __launch_bounds__(256) void transpose_w8(
    const void* w0, const void* w1, const void* w2, const void* w3,
    const void* w4, const void* w5, const void* w6, const void* w7,
    u16* __restrict__ wt1, u16* __restrict__ wt2,
    u16* __restrict__ f1t, u16* __restrict__ f2t,
    const int* __restrict__ flag)
{
    const int z = blockIdx.z;
    int K, M; const void* src; u16* dst;
    switch (z) {
        case 0: K=256;  M=512;  src=w0; dst=wt1;               break; // qW1
        case 1: K=256;  M=512;  src=w1; dst=wt1 + 512*256;     break; // kW1
        case 2: K=256;  M=512;  src=w2; dst=wt1 + 2*512*256;   break; // vW1
        case 3: K=512;  M=512;  src=w3; dst=wt2;               break; // qW2
        case 4: K=512;  M=512;  src=w4; dst=wt2 + 512*512;     break; // kW2
        case 5: K=512;  M=512;  src=w5; dst=wt2 + 2*512*512;   break; // vW2
        case 6: K=512;  M=1024; src=w6; dst=f1t;               break; // fW1
        default: K=1024; M=512; src=w7; dst=f2t;               break; // fW2
    }
    const int m0 = blockIdx.x * 32, k0 = blockIdx.y * 32;
    if (m0 >= M || k0 >= K) return;
    __shared__ u16 t[32][33];
    const int tid = threadIdx.x, tx = tid & 31, ty = tid >> 5;
    const int isf = *flag;
    #pragma unroll
    for (int i = 0; i < 4; ++i) {
        const int kk = k0 + ty + i * 8;
        t[ty + i * 8][tx] = isf ? f2bf(((const float*)src)[(size_t)kk * M + m0 + tx])
                                : ((const u16*)src)[(size_t)kk * M + m0 + tx];
    }
    __syncthreads();
    #pragma unroll
    for (int i = 0; i < 4; ++i) {
        const int mm = m0 + ty + i * 8;
        dst[(size_t)mm * K + k0 + tx] = t[tx][ty + i * 8];
    }
}

// v bf16 [B*S][EMB] -> Vt bf16 [B][H][HD][S]
__global__ __launch_bounds__(256) void transpose_v(
    const u16* __restrict__ v, u16* __restrict__ vt)
{
    __shared__ u16 t[32][33];
    const int tid = threadIdx.x, tx = tid & 31, ty = tid >> 5;
    const int s0 = blockIdx.x * 32, d0 = blockIdx.y * 32;
    const int bh = blockIdx.z, b = bh >> 3, h = bh & 7;
    #pragma unroll
    for (int i = 0; i < 4; ++i) {
        const int s = s0 + ty + i * 8;
        t[ty + i * 8][tx] = v[((size_t)b * SS + s) * EMB + h * HD + d0 + tx];
    }
    __syncthreads();
    #pragma unroll
    for (int i = 0; i < 4; ++i) {
        const int d = d0 + ty + i * 8;
        vt[((size_t)bh * HD + d) * SS + s0 + tx] = t[tx][ty + i * 8];
    }
}

// ---------------------------------------------------------------------------
// MFMA GEMM: out[N,M] = act(A[N,K] @ Wt[M,K]^T + bias), bf16 in/out.
// 128x128 tile, BK=32, 4 waves, XOR-swizzled LDS, global_load_lds w=16.
// ---------------------------------------------------------------------------
template <bool RELU, bool AWHICH>
__global__ __launch_bounds__(256) void gemm_bt(
    const u16* __restrict__ Aall, const u16* __restrict__ Wtall,
    const float* __restrict__ ball, u16* __restrict__ out,
    int N, int K, int M)
{
    __shared__ __align__(16) u16 sA[128 * 32];
    __shared__ __align__(16) u16 sB[128 * 32];

    const int mtiles = M >> 7;
    const int which = blockIdx.x / mtiles;
    const int colb  = blockIdx.x % mtiles;
    const int row0 = blockIdx.y << 7, col0 = colb << 7;
    const u16* A  = Aall + (AWHICH ? (size_t)which * N * K : 0);
    const u16* Wt = Wtall + (size_t)which * M * K;
    const float* bias = ball + (size_t)which * M;

    const int tid = threadIdx.x;
    const int lane = tid & 63, w = tid >> 6;
    const int wrow = (w & 1) << 6, wcol = (w >> 1) << 6;
    const int c = lane & 15, quad = lane >> 4;

    f32x4 acc[4][4] = {};

    for (int k0 = 0; k0 < K; k0 += 32) {
        __syncthreads();
        #pragma unroll
        for (int i = 0; i < 2; ++i) {
            const int raw = i * 256 + tid;
            const int r = raw >> 2, swz = raw & 3;
            const int ch = swz ^ (r & 3);
            async16(A + (size_t)(row0 + r) * K + k0 + ch * 8, (char*)sA + raw * 16);
        }
        #pragma unroll
        for (int i = 0; i < 2; ++i) {
            const int raw = i * 256 + tid;
            const int r = raw >> 2, swz = raw & 3;
            const int ch = swz ^ (r & 3);
            async16(Wt + (size_t)(col0 + r) * K + k0 + ch * 8, (char*)sB + raw * 16);
        }
        __syncthreads();

        bf16x8 af[4], bfr[4];
        #pragma unroll
        for (int rt = 0; rt < 4; ++rt) {
            const int r = wrow + rt * 16 + c;
            af[rt] = *(const bf16x8*)&sA[(r * 4 + (quad ^ (r & 3))) * 8];
        }
        #pragma unroll
        for (int ct = 0; ct < 4; ++ct) {
            const int r = wcol + ct * 16 + c;
            bfr[ct] = *(const bf16x8*)&sB[(r * 4 + (quad ^ (r & 3))) * 8];
        }
        #pragma unroll
        for (int rt = 0; rt < 4; ++rt)
            #pragma unroll
            for (int ct = 0; ct < 4; ++ct)
                acc[rt][ct] = __builtin_amdgcn_mfma_f32_16x16x32_bf16(
                    af[rt], bfr[ct], acc[rt][ct], 0, 0, 0);
    }

    const size_t outW = (size_t)which * N * M;
    #pragma unroll
    for (int rt = 0; rt < 4; ++rt) {
        #pragma unroll
        for (int i = 0; i < 4; ++i) {
            const int row = row0 + wrow + rt * 16 + quad * 4 + i;
            #pragma unroll
            for (int ct = 0; ct < 4; ++ct) {
                const int col = col0 + wcol + ct * 16 + c;
                float v = acc[rt][ct][i] + bias[col];
                if (RELU) v = fmaxf(v, 0.0f);
                out[outW + (size_t)row * M + col] = f2bf(v);
            }
        }
    }
}

// ---------------------------------------------------------------------------
// MFMA flash attention, no-max softmax (shift-invariant; scores sigma ~0.2,
// clamped at +50 to guard overflow). Per-lane l accumulator, reduced once.
// Block = 4 waves x 16 queries, loops 64-key tiles. ctx out bf16.
// ---------------------------------------------------------------------------
__global__ __launch_bounds__(256) void attn_mfma(
    const u16* __restrict__ q, const u16* __restrict__ k,
    const u16* __restrict__ vt, u16* __restrict__ ctx)
{
    __shared__ __align__(16) u16 sK[64 * 64];
    __shared__ __align__(16) u16 sV[64 * 64];
    __shared__ __align__(16) u16 sP[4][16 * 64];

    const int tid = threadIdx.x;
    const int w = tid >> 6, lane = tid & 63;
    const int c = lane & 15, quad = lane >> 4;
    const int q0 = blockIdx.x * 64;
    const int h = blockIdx.y, b = blockIdx.z;
    const size_t tokbase = (size_t)b * SS;
    const int hoff = h * HD;
    const size_t vtbase = (size_t)(b * NH + h) * HD * SS;

    // Q B-fragments in registers (2 K-chunks of 32)
    const int myq = q0 + w * 16 + c;
    bf16x8 qf[2];
    #pragma unroll
    for (int kt = 0; kt < 2; ++kt)
        qf[kt] = *(const bf16x8*)&q[(tokbase + myq) * EMB + hoff + kt * 32 + quad * 8];

    float l_lane = 0.0f;
    f32x4 accO[4] = {};

    for (int t = 0; t < SS / 64; ++t) {
        const int j0 = t * 64;
        __syncthreads();
        #pragma unroll
        for (int i = 0; i < 2; ++i) {
            const int raw = i * 256 + tid;
            const int key = raw >> 3, swz = raw & 7;
            const int ch = swz ^ (key & 7);
            async16(&k[(tokbase + j0 + key) * EMB + hoff + ch * 8], (char*)sK + raw * 16);
        }
        #pragma unroll
        for (int i = 0; i < 2; ++i) {
            const int raw = i * 256 + tid;
            const int d = raw >> 3, swz = raw & 7;
            const int ch = swz ^ (d & 7);
            async16(&vt[vtbase + (size_t)d * SS + j0 + ch * 8], (char*)sV + raw * 16);
        }
        __syncthreads();

        // S^T[key][q]: A = K-tile, B = Q^T
        f32x4 accS[4] = {};
        #pragma unroll
        for (int mt = 0; mt < 4; ++mt) {
            const int key = mt * 16 + c;
            #pragma unroll
            for (int kt = 0; kt < 2; ++kt) {
                bf16x8 kf = *(const bf16x8*)&sK[(key * 8 + ((quad + 4 * kt) ^ (key & 7))) * 8];
                accS[mt] = __builtin_amdgcn_mfma_f32_16x16x32_bf16(kf, qf[kt], accS[mt], 0, 0, 0);
            }
        }

        // p = exp(s*SCALE) = exp2(s*C2), no max subtraction
        u16 ph[16];
        #pragma unroll
        for (int mt = 0; mt < 4; ++mt)
            #pragma unroll
            for (int i = 0; i < 4; ++i) {
                const float p = exp2f(fminf(accS[mt][i] * C2, 50.0f));
                l_lane += p;
                ph[mt * 4 + i] = f2bf(p);
            }

        // write P^T -> sP[w][q=c][key], swizzled blocks of 8 halves
        #pragma unroll
        for (int mt = 0; mt < 4; ++mt) {
            const int chunkW = (quad >> 1) + 2 * mt;
            const int blk = c * 8 + (chunkW ^ (c & 7));
            uint2 pw;
            pw.x = (unsigned)ph[mt * 4] | ((unsigned)ph[mt * 4 + 1] << 16);
            pw.y = (unsigned)ph[mt * 4 + 2] | ((unsigned)ph[mt * 4 + 3] << 16);
            *(uint2*)((char*)&sP[w][0] + blk * 16 + 8 * (quad & 1)) = pw;
        }

        // PV: A = P (per-wave LDS round trip), B = V via Vt tile
        bf16x8 pf[2];
        #pragma unroll
        for (int kt = 0; kt < 2; ++kt)
            pf[kt] = *(const bf16x8*)&sP[w][(c * 8 + ((quad + 4 * kt) ^ (c & 7))) * 8];
        #pragma unroll
        for (int nt = 0; nt < 4; ++nt) {
            const int d = nt * 16 + c;
            #pragma unroll
            for (int kt = 0; kt < 2; ++kt) {
                bf16x8 vf = *(const bf16x8*)&sV[(d * 8 + ((quad + 4 * kt) ^ (d & 7))) * 8];
                accO[nt] = __builtin_amdgcn_mfma_f32_16x16x32_bf16(pf[kt], vf, accO[nt], 0, 0, 0);
            }
        }
    }

    // reduce l over quads (query = c), then broadcast per output row
    float l = l_lane;
    l += __shfl_xor(l, 16);
    l += __shfl_xor(l, 32);
    float li[4];
    #pragma unroll
    for (int i = 0; i < 4; ++i) {
        const float lv = __shfl(l, quad * 4 + i, 16);
        li[i] = (lv > 0.0f) ? (1.0f / lv) : 0.0f;
    }
    #pragma unroll
    for (int nt = 0; nt < 4; ++nt)
        #pragma unroll
        for (int i = 0; i < 4; ++i) {
            const int tok = q0 + w * 16 + quad * 4 + i;
            ctx[(tokbase + tok) * EMB + hoff + nt * 16 + c] = f2bf(accO[nt][i] * li[i]);
        }
}

// ---------------------------------------------------------------------------
// Residual + LayerNorm over EMB=512, bf16 in, vectorized loads.
// ---------------------------------------------------------------------------
__global__ __launch_bounds__(256) void ln_mid(
    const u16* __restrict__ a, const u16* __restrict__ b2,
    const float* __restrict__ g, const float* __restrict__ be,
    u16* __restrict__ outb)
{
    const int wave = threadIdx.x >> 6, lane = threadIdx.x & 63;
    const size_t row = (size_t)blockIdx.x * 4 + wave;
    const u16x8 av = *(const u16x8*)&a[row * EMB + lane * 8];
    const u16x8 bv = *(const u16x8*)&b2[row * EMB + lane * 8];
    float vals[8], sum = 0.0f;
    #pragma unroll
    for (int i = 0; i < 8; ++i) { vals[i] = bf2f(av[i]) + bf2f(bv[i]); sum += vals[i]; }
    #pragma unroll
    for (int o = 1; o < 64; o <<= 1) sum += __shfl_xor(sum, o);
    const float mu = sum * (1.0f / 512.0f);
    float vs = 0.0f;
    #pragma unroll
    for (int i = 0; i < 8; ++i) { const float d = vals[i] - mu; vs += d * d; }
    #pragma unroll
    for (int o = 1; o < 64; o <<= 1) vs += __shfl_xor(vs, o);
    const float rstd = rsqrtf(vs * (1.0f / 512.0f) + EPS);
    u16x8 ov;
    #pragma unroll
    for (int i = 0; i < 8; ++i) {
        const int col = lane * 8 + i;
        ov[i] = f2bf((vals[i] - mu) * rstd * g[col] + be[col]);
    }
    *(u16x8*)&outb[row * EMB + lane * 8] = ov;
}

__global__ __launch_bounds__(256) void ln_final(
    const u16* __restrict__ a, const u16* __restrict__ b2,
    const float* __restrict__ g, const float* __restrict__ be,
    void* __restrict__ dout, const int* __restrict__ flag)
{
    const int wave = threadIdx.x >> 6, lane = threadIdx.x & 63;
    const size_t row = (size_t)blockIdx.x * 4 + wave;
    const u16x8 av = *(const u16x8*)&a[row * EMB + lane * 8];
    const u16x8 bv = *(const u16x8*)&b2[row * EMB + lane * 8];
    float vals[8], sum = 0.0f;
    #pragma unroll
    for (int i = 0; i < 8; ++i) { vals[i] = bf2f(av[i]) + bf2f(bv[i]); sum += vals[i]; }
    #pragma unroll
    for (int o = 1; o < 64; o <<= 1) sum += __shfl_xor(sum, o);
    const float mu = sum * (1.0f / 512.0f);
    float vs = 0.0f;
    #pragma unroll
    for (int i = 0; i < 8; ++i) { const float d = vals[i] - mu; vs += d * d; }
    #pragma unroll
    for (int o = 1; o < 64; o <<= 1) vs += __shfl_xor(vs, o);
    const float rstd = rsqrtf(vs * (1.0f / 512.0f) + EPS);
    const int isf = *flag;
    if (isf) {
        #pragma unroll
        for (int i = 0; i < 8; ++i) {
            const int col = lane * 8 + i;
            ((float*)dout)[row * EMB + col] = (vals[i] - mu) * rstd * g[col] + be[col];
        }
    } else {
        u16x8 ov;
        #pragma unroll
        for (int i = 0; i < 8; ++i) {
            const int col = lane * 8 + i;
            ov[i] = f2bf((vals[i] - mu) * rstd * g[col] + be[col]);
        }
        *(u16x8*)&((u16*)dout)[row * EMB + lane * 8] = ov;
    }
}

// ---------------------------------------------------------------------------
extern "C" void kernel_launch(void* const* d_in, const int* in_sizes, int n_in,
                              void* d_out, int out_size, void* d_ws, size_t ws_size,
                              hipStream_t stream)
{
    char* ws = (char*)d_ws;
    int*   flag  = (int*)(ws + 0);
    float* small = (float*)(ws + 256);
    u16*   wt1   = (u16*)(ws + 32768);
    u16*   wt2   = (u16*)(ws + 819200);
    u16*   f1t   = (u16*)(ws + 2392064);
    u16*   f2t   = (u16*)(ws + 3440640);
    u16*   xbf   = (u16*)(ws + 4489216);
    u16*   h3    = (u16*)(ws + 8683520);    // [3][NT][512]; reused as h2 [NT][1024]
    u16*   qkv   = (u16*)(ws + 33849344);   // [3][NT][512]
    u16*   vtb   = (u16*)(ws + 59015168);   // [B][H][64][S]
    u16*   ctxb  = (u16*)(ws + 67403776);   // [NT][512] bf16
    u16*   x1b   = (u16*)(ws + 75792384);   // [NT][512] bf16
    u16*   ffb   = (u16*)(ws + 84180992);   // [NT][512] bf16

    const dim3 blk(256);

    detect_dtype<<<1, blk, 0, stream>>>((const u16*)d_in[0], flag);
    conv_x<<<(NT * INF_ + 255) / 256, blk, 0, stream>>>(d_in[0], xbf, NT * INF_, flag);
    transpose_w8<<<dim3(32, 32, 8), blk, 0, stream>>>(
        d_in[1], d_in[5], d_in[9], d_in[3], d_in[7], d_in[11], d_in[13], d_in[15],
        wt1, wt2, f1t, f2t, flag);
    conv_small<<<dim3(4, 12), blk, 0, stream>>>(
        d_in[2], d_in[4], d_in[6], d_in[8], d_in[10], d_in[12],
        d_in[14], d_in[16], d_in[17], d_in[18], d_in[19], d_in[20], small, flag);

    // qkv layer 1: h3[which] = relu(x @ W1 + b1)
    gemm_bt<true, false><<<dim3(12, 64), blk, 0, stream>>>(
        xbf, wt1, small + 0, h3, NT, INF_, EMB);
    // qkv layer 2: qkv[which] = h3[which] @ W2 + b2
    gemm_bt<false, true><<<dim3(12, 64), blk, 0, stream>>>(
        h3, wt2, small + 1536, qkv, NT, EMB, EMB);

    transpose_v<<<dim3(64, 2, 32), blk, 0, stream>>>(qkv + 2 * (size_t)NT * EMB, vtb);

    attn_mfma<<<dim3(SS / 64, NH, BB), blk, 0, stream>>>(
        qkv, qkv + (size_t)NT * EMB, vtb, ctxb);

    // x1 = LN(ctx + q)  (q residual = bf16 qkv[0])
    ln_mid<<<NT / 4, blk, 0, stream>>>(ctxb, qkv, small + 4608, small + 5120, x1b);

    // FFN
    u16* h2 = h3;
    gemm_bt<true, false><<<dim3(8, 64), blk, 0, stream>>>(
        x1b, f1t, small + 3072, h2, NT, EMB, 1024);
    gemm_bt<false, false><<<dim3(4, 64), blk, 0, stream>>>(
        h2, f2t, small + 4096, ffb, NT, 1024, EMB);

    // out = LN(x1 + ff)
    ln_final<<<NT / 4, blk, 0, stream>>>(x1b, ffb, small + 5632, small + 6144, d_out, flag);
}

// Round 5
// 263.124 us; speedup vs baseline: 9.4884x; 1.1101x over previous
//
#include <hip/hip_runtime.h>
#include <hip/hip_bf16.h>
#include <math.h>

#define BB   4
#define SS   2048
#define INF_ 256
#define EMB  512
#define NH   8
#define HD   64
#define NT   8192

typedef unsigned short u16;
typedef unsigned int   u32;
typedef __attribute__((ext_vector_type(8))) short bf16x8;   // 8 bf16 = 4 VGPRs
typedef __attribute__((ext_vector_type(8))) unsigned short u16x8;
typedef __attribute__((ext_vector_type(4))) float f32x4;

constexpr float C2  = 0.06375871607f;    // (1/sqrt(512)) * log2(e)
constexpr float RB  = 0.005624549f;      // log2(1 + 2^-8): half-ulp pre-bias for trunc pack
constexpr float TB  = 1.00390625f;       // 1 + 2^-8
constexpr float EPS = 1e-5f;

__device__ __forceinline__ u16 f2bf(float v) {          // RNE (used in LN only)
    __hip_bfloat16 h = __float2bfloat16(v);
    return *(u16*)&h;
}
__device__ __forceinline__ float bf2f(u16 u) {
    __hip_bfloat16 h = *(__hip_bfloat16*)&u;
    return __bfloat162float(h);
}
// truncate-to-bf16 with half-ulp bias: error band == RNE band
__device__ __forceinline__ u16 ftrunc_bf(float v) {
    return (u16)(__float_as_uint(v * TB) >> 16);
}
__device__ __forceinline__ f32x4 mfma16(bf16x8 a, bf16x8 b, f32x4 c) {
    return __builtin_amdgcn_mfma_f32_16x16x32_bf16(a, b, c, 0, 0, 0);
}
// async global->LDS, 16B per lane (m97 idiom)
__device__ __forceinline__ void async16(const void* g, void* l) {
    __builtin_amdgcn_global_load_lds(
        (const __attribute__((address_space(1))) void*)g,
        (__attribute__((address_space(3))) void*)l, 16, 0, 0);
}
// per-block dtype vote: 1 -> fp32 inputs, 0 -> bf16 (deterministic, all waves agree)
__device__ __forceinline__ int derive_flag(const u16* x) {
    const int lane = threadIdx.x & 63;
    const unsigned e = (x[lane * 2] >> 7) & 0xFF;
    float pl = (e == 0 || (e >= 110 && e <= 140)) ? 1.0f : 0.0f;
    #pragma unroll
    for (int o = 1; o < 64; o <<= 1) pl += __shfl_xor(pl, o);
    return pl < 32.0f;
}

// ---------------------------------------------------------------------------
// Fused prep: z 0..7 weight transpose W[K][M]->Wt[M][K] bf16; z=8 x->bf16;
// z=9 biases/ln params -> packed f32. Each block derives the flag itself.
// ---------------------------------------------------------------------------
__global__ __launch_bounds__(256) void prep(
    const u16* __restrict__ xsrc,
    const void* w0, const void* w1, const void* w2, const void* w3,
    const void* w4, const void* w5, const void* w6, const void* w7,
    const void* p0, const void* p1, const void* p2, const void* p3,
    const void* p4, const void* p5, const void* p6, const void* p7,
    const void* p8, const void* p9, const void* p10, const void* p11,
    u16* __restrict__ xbf, u16* __restrict__ wt1, u16* __restrict__ wt2,
    u16* __restrict__ f1t, u16* __restrict__ f2t, float* __restrict__ small)
{
    const int isf = derive_flag(xsrc);
    const int z = blockIdx.z;
    const int tid = threadIdx.x;

    if (z < 8) {
        int K, M; const void* src; u16* dst;
        switch (z) {
            case 0: K=256;  M=512;  src=w0; dst=wt1;             break;
            case 1: K=256;  M=512;  src=w1; dst=wt1+512*256;     break;
            case 2: K=256;  M=512;  src=w2; dst=wt1+2*512*256;   break;
            case 3: K=512;  M=512;  src=w3; dst=wt2;             break;
            case 4: K=512;  M=512;  src=w4; dst=wt2+512*512;     break;
            case 5: K=512;  M=512;  src=w5; dst=wt2+2*512*512;   break;
            case 6: K=512;  M=1024; src=w6; dst=f1t;             break;
            default:K=1024; M=512;  src=w7; dst=f2t;             break;
        }
        const int m0 = blockIdx.x * 32, k0 = blockIdx.y * 32;
        if (m0 >= M || k0 >= K) return;
        __shared__ u16 t[32][33];
        const int tx = tid & 31, ty = tid >> 5;
        #pragma unroll
        for (int i = 0; i < 4; ++i) {
            const int kk = k0 + ty + i * 8;
            t[ty + i * 8][tx] = isf ? ftrunc_bf(((const float*)src)[(size_t)kk * M + m0 + tx])
                                    : ((const u16*)src)[(size_t)kk * M + m0 + tx];
        }
        __syncthreads();
        #pragma unroll
        for (int i = 0; i < 4; ++i) {
            const int mm = m0 + ty + i * 8;
            dst[(size_t)mm * K + k0 + tx] = t[tx][ty + i * 8];
        }
    } else if (z == 8) {
        const int bid = blockIdx.y * 32 + blockIdx.x;    // 0..1023
        const int base = bid * 2048 + tid * 8;           // NT*INF_ = 2M elems
        if (isf) {
            #pragma unroll
            for (int j = 0; j < 8; ++j)
                xbf[base + j] = ftrunc_bf(((const float*)xsrc)[base + j]);
        } else {
            *(u16x8*)&xbf[base] = *(const u16x8*)&xsrc[base];
        }
    } else {
        const int bid = blockIdx.y * 32 + blockIdx.x;
        if (bid >= 28) return;                           // 7168 packed f32
        const int e = bid * 256 + tid;
        int id, i;
        if (e < 3072)      { id = e >> 9;               i = e & 511;          }
        else if (e < 4096) { id = 6;                    i = e - 3072;         }
        else               { id = 7 + ((e - 4096) >> 9); i = (e - 4096) & 511; }
        const void* src;
        switch (id) {
            case 0: src = p0; break;  case 1: src = p1; break;
            case 2: src = p2; break;  case 3: src = p3; break;
            case 4: src = p4; break;  case 5: src = p5; break;
            case 6: src = p6; break;  case 7: src = p7; break;
            case 8: src = p8; break;  case 9: src = p9; break;
            case 10: src = p10; break; default: src = p11; break;
        }
        small[e] = isf ? ((const float*)src)[i] : bf2f(((const u16*)src)[i]);
    }
}

// v bf16 [B*S][EMB] -> Vt bf16 [B][H][HD][S]
__global__ __launch_bounds__(256) void transpose_v(
    const u16* __restrict__ v, u16* __restrict__ vt)
{
    __shared__ u16 t[32][33];
    const int tid = threadIdx.x, tx = tid & 31, ty = tid >> 5;
    const int s0 = blockIdx.x * 32, d0 = blockIdx.y * 32;
    const int bh = blockIdx.z, b = bh >> 3, h = bh & 7;
    #pragma unroll
    for (int i = 0; i < 4; ++i) {
        const int s = s0 + ty + i * 8;
        t[ty + i * 8][tx] = v[((size_t)b * SS + s) * EMB + h * HD + d0 + tx];
    }
    __syncthreads();
    #pragma unroll
    for (int i = 0; i < 4; ++i) {
        const int d = d0 + ty + i * 8;
        vt[((size_t)bh * HD + d) * SS + s0 + tx] = t[tx][ty + i * 8];
    }
}

// ---------------------------------------------------------------------------
// MFMA GEMM: out[N,M] = act(A[N,K] @ Wt[M,K]^T + bias). TRxTC tile, BK=64,
// 2x2 waves, XOR-swizzled LDS, global_load_lds w=16, hoisted stage pointers.
// ---------------------------------------------------------------------------
template <int TR, int TC, bool RELU, bool AWHICH>
__global__ __launch_bounds__(256) void gemm_bt(
    const u16* __restrict__ Aall, const u16* __restrict__ Wtall,
    const float* __restrict__ ball, u16* __restrict__ out,
    int N, int K, int M)
{
    constexpr int RT = TR / 32, CT = TC / 32;
    constexpr int AR = TR / 32, BR = TC / 32;    // staging rounds (2048 elems each)
    __shared__ __align__(16) u16 sA[TR * 64];
    __shared__ __align__(16) u16 sB[TC * 64];

    const int mtiles = M / TC;
    const int which = blockIdx.x / mtiles;
    const int colb  = blockIdx.x % mtiles;
    const int row0 = blockIdx.y * TR, col0 = colb * TC;
    const u16* A  = Aall + (AWHICH ? (size_t)which * N * K : 0);
    const u16* Wt = Wtall + (size_t)which * M * K;
    const float* bias = ball + (size_t)which * M;

    const int tid = threadIdx.x;
    const int lane = tid & 63, w = tid >> 6;
    const int wrow = (w & 1) * (TR / 2), wcol = (w >> 1) * (TC / 2);
    const int c = lane & 15, quad = lane >> 4;

    const u16* ap[AR]; const u16* bp[BR];
    #pragma unroll
    for (int i = 0; i < AR; ++i) {
        const int raw = i * 256 + tid, r = raw >> 3, ch = (raw & 7) ^ (r & 7);
        ap[i] = A + (size_t)(row0 + r) * K + ch * 8;
    }
    #pragma unroll
    for (int i = 0; i < BR; ++i) {
        const int raw = i * 256 + tid, r = raw >> 3, ch = (raw & 7) ^ (r & 7);
        bp[i] = Wt + (size_t)(col0 + r) * K + ch * 8;
    }

    f32x4 acc[RT][CT] = {};

    for (int k0 = 0; k0 < K; k0 += 64) {
        __syncthreads();
        #pragma unroll
        for (int i = 0; i < AR; ++i) {
            async16(ap[i], (char*)sA + (i * 256 + tid) * 16);
            ap[i] += 64;
        }
        #pragma unroll
        for (int i = 0; i < BR; ++i) {
            async16(bp[i], (char*)sB + (i * 256 + tid) * 16);
            bp[i] += 64;
        }
        __syncthreads();

        #pragma unroll
        for (int kt = 0; kt < 2; ++kt) {
            bf16x8 af[RT], bfr[CT];
            #pragma unroll
            for (int rt = 0; rt < RT; ++rt) {
                const int r = wrow + rt * 16 + c;
                af[rt] = *(const bf16x8*)&sA[(r * 8 + ((kt * 4 + quad) ^ (r & 7))) * 8];
            }
            #pragma unroll
            for (int ct = 0; ct < CT; ++ct) {
                const int r = wcol + ct * 16 + c;
                bfr[ct] = *(const bf16x8*)&sB[(r * 8 + ((kt * 4 + quad) ^ (r & 7))) * 8];
            }
            #pragma unroll
            for (int rt = 0; rt < RT; ++rt)
                #pragma unroll
                for (int ct = 0; ct < CT; ++ct)
                    acc[rt][ct] = mfma16(af[rt], bfr[ct], acc[rt][ct]);
        }
    }

    const size_t outW = (size_t)which * N * M;
    #pragma unroll
    for (int rt = 0; rt < RT; ++rt) {
        #pragma unroll
        for (int i = 0; i < 4; ++i) {
            const int row = row0 + wrow + rt * 16 + quad * 4 + i;
            #pragma unroll
            for (int ct = 0; ct < CT; ++ct) {
                const int col = col0 + wcol + ct * 16 + c;
                float v = acc[rt][ct][i] + bias[col];
                if (RELU) v = fmaxf(v, 0.0f);
                out[outW + (size_t)row * M + col] = (u16)(__float_as_uint(v * TB) >> 16);
            }
        }
    }
}

// ---------------------------------------------------------------------------
// MFMA flash attention, no-max softmax in log2 domain:
// p = exp2(fma(s, C2, RB)); perm-pack to bf16 (trunc + half-ulp pre-bias).
// Block = 4 waves x 16 queries, 64-key tiles, hoisted stage pointers.
// ---------------------------------------------------------------------------
__global__ __launch_bounds__(256) void attn_mfma(
    const u16* __restrict__ q, const u16* __restrict__ k,
    const u16* __restrict__ vt, u16* __restrict__ ctx)
{
    __shared__ __align__(16) u16 sK[64 * 64];
    __shared__ __align__(16) u16 sV[64 * 64];
    __shared__ __align__(16) u16 sP[4][16 * 64];

    const int tid = threadIdx.x;
    const int w = tid >> 6, lane = tid & 63;
    const int c = lane & 15, quad = lane >> 4;
    const int q0 = blockIdx.x * 64;
    const int h = blockIdx.y, b = blockIdx.z;
    const size_t tokbase = (size_t)b * SS;
    const int hoff = h * HD;

    const int myq = q0 + w * 16 + c;
    bf16x8 qf[2];
    #pragma unroll
    for (int kt = 0; kt < 2; ++kt)
        qf[kt] = *(const bf16x8*)&q[(tokbase + myq) * EMB + hoff + kt * 32 + quad * 8];

    const u16* kp[2]; const u16* vp[2];
    #pragma unroll
    for (int i = 0; i < 2; ++i) {
        const int raw = i * 256 + tid, rr = raw >> 3, ch = (raw & 7) ^ (rr & 7);
        kp[i] = k + (tokbase + rr) * EMB + hoff + ch * 8;
        vp[i] = vt + ((size_t)(b * NH + h) * HD + rr) * SS + ch * 8;
    }

    float l_lane = 0.0f;
    f32x4 accO[4] = {};

    for (int t = 0; t < SS / 64; ++t) {
        __syncthreads();
        #pragma unroll
        for (int i = 0; i < 2; ++i) {
            async16(kp[i], (char*)sK + (i * 256 + tid) * 16);
            kp[i] += 64 * EMB;
        }
        #pragma unroll
        for (int i = 0; i < 2; ++i) {
            async16(vp[i], (char*)sV + (i * 256 + tid) * 16);
            vp[i] += 64;
        }
        __syncthreads();

        // S^T[key][q]: A = K-tile, B = Q^T
        f32x4 accS[4] = {};
        #pragma unroll
        for (int mt = 0; mt < 4; ++mt) {
            const int key = mt * 16 + c;
            #pragma unroll
            for (int kt = 0; kt < 2; ++kt) {
                bf16x8 kf = *(const bf16x8*)&sK[(key * 8 + ((kt * 4 + quad) ^ (key & 7))) * 8];
                accS[mt] = mfma16(kf, qf[kt], accS[mt]);
            }
        }

        // p = exp2(s*C2 + RB); pack pairs via v_perm (truncation, pre-biased)
        u32 pw[8];
        float ls = 0.0f;
        #pragma unroll
        for (int mt = 0; mt < 4; ++mt) {
            const float e0 = __builtin_amdgcn_exp2f(fmaf(accS[mt][0], C2, RB));
            const float e1 = __builtin_amdgcn_exp2f(fmaf(accS[mt][1], C2, RB));
            const float e2 = __builtin_amdgcn_exp2f(fmaf(accS[mt][2], C2, RB));
            const float e3 = __builtin_amdgcn_exp2f(fmaf(accS[mt][3], C2, RB));
            ls += (e0 + e1) + (e2 + e3);
            pw[2 * mt]     = __builtin_amdgcn_perm(__float_as_uint(e1), __float_as_uint(e0), 0x07060302u);
            pw[2 * mt + 1] = __builtin_amdgcn_perm(__float_as_uint(e3), __float_as_uint(e2), 0x07060302u);
        }
        l_lane += ls;

        // write P^T -> sP[w][q=c][key], swizzled blocks of 8 halves
        #pragma unroll
        for (int mt = 0; mt < 4; ++mt) {
            const int chunkW = (quad >> 1) + 2 * mt;
            const int blk = c * 8 + (chunkW ^ (c & 7));
            uint2 u; u.x = pw[2 * mt]; u.y = pw[2 * mt + 1];
            *(uint2*)((char*)&sP[w][0] + blk * 16 + 8 * (quad & 1)) = u;
        }

        // PV: A = P (per-wave LDS round trip), B = V via Vt tile
        bf16x8 pf[2];
        #pragma unroll
        for (int kt = 0; kt < 2; ++kt)
            pf[kt] = *(const bf16x8*)&sP[w][(c * 8 + ((kt * 4 + quad) ^ (c & 7))) * 8];
        #pragma unroll
        for (int nt = 0; nt < 4; ++nt) {
            const int d = nt * 16 + c;
            #pragma unroll
            for (int kt = 0; kt < 2; ++kt) {
                bf16x8 vf = *(const bf16x8*)&sV[(d * 8 + ((kt * 4 + quad) ^ (d & 7))) * 8];
                accO[nt] = mfma16(pf[kt], vf, accO[nt]);
            }
        }
    }

    float l = l_lane;
    l += __shfl_xor(l, 16);
    l += __shfl_xor(l, 32);
    float li[4];
    #pragma unroll
    for (int i = 0; i < 4; ++i) {
        const float lv = __shfl(l, quad * 4 + i, 16);
        li[i] = (lv > 0.0f) ? (1.0f / lv) : 0.0f;
    }
    #pragma unroll
    for (int nt = 0; nt < 4; ++nt)
        #pragma unroll
        for (int i = 0; i < 4; ++i) {
            const int tok = q0 + w * 16 + quad * 4 + i;
            ctx[(tokbase + tok) * EMB + hoff + nt * 16 + c] =
                (u16)(__float_as_uint(accO[nt][i] * li[i] * TB) >> 16);
        }
}

// ---------------------------------------------------------------------------
// Residual + LayerNorm over EMB=512, bf16 in, one wave per row.
// ---------------------------------------------------------------------------
__global__ __launch_bounds__(256) void ln_mid(
    const u16* __restrict__ a, const u16* __restrict__ b2,
    const float* __restrict__ g, const float* __restrict__ be,
    u16* __restrict__ outb)
{
    const int wave = threadIdx.x >> 6, lane = threadIdx.x & 63;
    const size_t row = (size_t)blockIdx.x * 4 + wave;
    const u16x8 av = *(const u16x8*)&a[row * EMB + lane * 8];
    const u16x8 bv = *(const u16x8*)&b2[row * EMB + lane * 8];
    float vals[8], sum = 0.0f;
    #pragma unroll
    for (int i = 0; i < 8; ++i) { vals[i] = bf2f(av[i]) + bf2f(bv[i]); sum += vals[i]; }
    #pragma unroll
    for (int o = 1; o < 64; o <<= 1) sum += __shfl_xor(sum, o);
    const float mu = sum * (1.0f / 512.0f);
    float vs = 0.0f;
    #pragma unroll
    for (int i = 0; i < 8; ++i) { const float d = vals[i] - mu; vs += d * d; }
    #pragma unroll
    for (int o = 1; o < 64; o <<= 1) vs += __shfl_xor(vs, o);
    const float rstd = rsqrtf(vs * (1.0f / 512.0f) + EPS);
    u16x8 ov;
    #pragma unroll
    for (int i = 0; i < 8; ++i) {
        const int col = lane * 8 + i;
        ov[i] = f2bf((vals[i] - mu) * rstd * g[col] + be[col]);
    }
    *(u16x8*)&outb[row * EMB + lane * 8] = ov;
}

__global__ __launch_bounds__(256) void ln_final(
    const u16* __restrict__ a, const u16* __restrict__ b2,
    const float* __restrict__ g, const float* __restrict__ be,
    void* __restrict__ dout, const u16* __restrict__ xsrc)
{
    const int isf = derive_flag(xsrc);
    const int wave = threadIdx.x >> 6, lane = threadIdx.x & 63;
    const size_t row = (size_t)blockIdx.x * 4 + wave;
    const u16x8 av = *(const u16x8*)&a[row * EMB + lane * 8];
    const u16x8 bv = *(const u16x8*)&b2[row * EMB + lane * 8];
    float vals[8], sum = 0.0f;
    #pragma unroll
    for (int i = 0; i < 8; ++i) { vals[i] = bf2f(av[i]) + bf2f(bv[i]); sum += vals[i]; }
    #pragma unroll
    for (int o = 1; o < 64; o <<= 1) sum += __shfl_xor(sum, o);
    const float mu = sum * (1.0f / 512.0f);
    float vs = 0.0f;
    #pragma unroll
    for (int i = 0; i < 8; ++i) { const float d = vals[i] - mu; vs += d * d; }
    #pragma unroll
    for (int o = 1; o < 64; o <<= 1) vs += __shfl_xor(vs, o);
    const float rstd = rsqrtf(vs * (1.0f / 512.0f) + EPS);
    if (isf) {
        #pragma unroll
        for (int i = 0; i < 8; ++i) {
            const int col = lane * 8 + i;
            ((float*)dout)[row * EMB + col] = (vals[i] - mu) * rstd * g[col] + be[col];
        }
    } else {
        u16x8 ov;
        #pragma unroll
        for (int i = 0; i < 8; ++i) {
            const int col = lane * 8 + i;
            ov[i] = f2bf((vals[i] - mu) * rstd * g[col] + be[col]);
        }
        *(u16x8*)&((u16*)dout)[row * EMB + lane * 8] = ov;
    }
}

// ---------------------------------------------------------------------------
extern "C" void kernel_launch(void* const* d_in, const int* in_sizes, int n_in,
                              void* d_out, int out_size, void* d_ws, size_t ws_size,
                              hipStream_t stream)
{
    char* ws = (char*)d_ws;
    float* small = (float*)(ws + 0);        // 7168 f32
    u16*   wt1   = (u16*)(ws + 32768);
    u16*   wt2   = (u16*)(ws + 819200);
    u16*   f1t   = (u16*)(ws + 2392064);
    u16*   f2t   = (u16*)(ws + 3440640);
    u16*   xbf   = (u16*)(ws + 4489216);
    u16*   h3    = (u16*)(ws + 8683520);    // [3][NT][512]; reused as h2 [NT][1024]
    u16*   qkv   = (u16*)(ws + 33849344);   // [3][NT][512]
    u16*   vtb   = (u16*)(ws + 59015168);   // [B][H][64][S]
    u16*   ctxb  = (u16*)(ws + 67403776);
    u16*   x1b   = (u16*)(ws + 75792384);
    u16*   ffb   = (u16*)(ws + 84180992);

    const dim3 blk(256);
    const u16* xsrc = (const u16*)d_in[0];

    prep<<<dim3(32, 32, 10), blk, 0, stream>>>(
        xsrc,
        d_in[1], d_in[5], d_in[9], d_in[3], d_in[7], d_in[11], d_in[13], d_in[15],
        d_in[2], d_in[6], d_in[10], d_in[4], d_in[8], d_in[12],
        d_in[14], d_in[16], d_in[17], d_in[18], d_in[19], d_in[20],
        xbf, wt1, wt2, f1t, f2t, small);

    // qkv layer 1: h3[which] = relu(x @ W1 + b1)
    gemm_bt<128, 128, true, false><<<dim3(12, 64), blk, 0, stream>>>(
        xbf, wt1, small + 0, h3, NT, INF_, EMB);
    // qkv layer 2: qkv[which] = h3[which] @ W2 + b2
    gemm_bt<128, 128, false, true><<<dim3(12, 64), blk, 0, stream>>>(
        h3, wt2, small + 1536, qkv, NT, EMB, EMB);

    transpose_v<<<dim3(64, 2, 32), blk, 0, stream>>>(qkv + 2 * (size_t)NT * EMB, vtb);

    attn_mfma<<<dim3(SS / 64, NH, BB), blk, 0, stream>>>(
        qkv, qkv + (size_t)NT * EMB, vtb, ctxb);

    // x1 = LN(ctx + q)
    ln_mid<<<NT / 4, blk, 0, stream>>>(ctxb, qkv, small + 4608, small + 5120, x1b);

    // FFN
    u16* h2 = h3;
    gemm_bt<128, 128, true, false><<<dim3(8, 64), blk, 0, stream>>>(
        x1b, f1t, small + 3072, h2, NT, EMB, 1024);
    gemm_bt<128, 64, false, false><<<dim3(8, 64), blk, 0, stream>>>(
        h2, f2t, small + 4096, ffb, NT, 1024, EMB);

    // out = LN(x1 + ff)
    ln_final<<<NT / 4, blk, 0, stream>>>(x1b, ffb, small + 5632, small + 6144, d_out, xsrc);
}

// Round 6
// 260.583 us; speedup vs baseline: 9.5809x; 1.0098x over previous
//
#include <hip/hip_runtime.h>
#include <hip/hip_bf16.h>
#include <math.h>

#define BB   4
#define SS   2048
#define INF_ 256
#define EMB  512
#define NH   8
#define HD   64
#define NT   8192

typedef unsigned short u16;
typedef unsigned int   u32;
typedef __attribute__((ext_vector_type(8))) short bf16x8;   // 8 bf16 = 4 VGPRs
typedef __attribute__((ext_vector_type(8))) unsigned short u16x8;
typedef __attribute__((ext_vector_type(4))) float f32x4;

constexpr float C2  = 0.06375871607f;    // (1/sqrt(512)) * log2(e)
constexpr float RB  = 0.005624549f;      // log2(1 + 2^-8): half-ulp pre-bias for trunc pack
constexpr float TB  = 1.00390625f;       // 1 + 2^-8
constexpr float EPS = 1e-5f;

__device__ __forceinline__ u16 f2bf(float v) {          // RNE (LN epilogues)
    __hip_bfloat16 h = __float2bfloat16(v);
    return *(u16*)&h;
}
__device__ __forceinline__ float bf2f(u16 u) {
    __hip_bfloat16 h = *(__hip_bfloat16*)&u;
    return __bfloat162float(h);
}
__device__ __forceinline__ u16 ftrunc_bf(float v) {     // trunc + half-ulp bias
    return (u16)(__float_as_uint(v * TB) >> 16);
}
__device__ __forceinline__ f32x4 mfma16(bf16x8 a, bf16x8 b, f32x4 c) {
    return __builtin_amdgcn_mfma_f32_16x16x32_bf16(a, b, c, 0, 0, 0);
}
__device__ __forceinline__ void async16(const void* g, void* l) {
    __builtin_amdgcn_global_load_lds(
        (const __attribute__((address_space(1))) void*)g,
        (__attribute__((address_space(3))) void*)l, 16, 0, 0);
}
// per-block dtype vote: 1 -> fp32 inputs, 0 -> bf16
__device__ __forceinline__ int derive_flag(const u16* x) {
    const int lane = threadIdx.x & 63;
    const unsigned e = (x[lane * 2] >> 7) & 0xFF;
    float pl = (e == 0 || (e >= 110 && e <= 140)) ? 1.0f : 0.0f;
    #pragma unroll
    for (int o = 1; o < 64; o <<= 1) pl += __shfl_xor(pl, o);
    return pl < 32.0f;
}

// ---------------------------------------------------------------------------
// Fused prep: z 0..7 weight transpose W[K][M]->Wt[M][K] bf16; z=8 x->bf16;
// z=9 biases/ln params -> packed f32.
// ---------------------------------------------------------------------------
__global__ __launch_bounds__(256) void prep(
    const u16* __restrict__ xsrc,
    const void* w0, const void* w1, const void* w2, const void* w3,
    const void* w4, const void* w5, const void* w6, const void* w7,
    const void* p0, const void* p1, const void* p2, const void* p3,
    const void* p4, const void* p5, const void* p6, const void* p7,
    const void* p8, const void* p9, const void* p10, const void* p11,
    u16* __restrict__ xbf, u16* __restrict__ wt1, u16* __restrict__ wt2,
    u16* __restrict__ f1t, u16* __restrict__ f2t, float* __restrict__ small)
{
    const int isf = derive_flag(xsrc);
    const int z = blockIdx.z;
    const int tid = threadIdx.x;

    if (z < 8) {
        int K, M; const void* src; u16* dst;
        switch (z) {
            case 0: K=256;  M=512;  src=w0; dst=wt1;             break;
            case 1: K=256;  M=512;  src=w1; dst=wt1+512*256;     break;
            case 2: K=256;  M=512;  src=w2; dst=wt1+2*512*256;   break;
            case 3: K=512;  M=512;  src=w3; dst=wt2;             break;
            case 4: K=512;  M=512;  src=w4; dst=wt2+512*512;     break;
            case 5: K=512;  M=512;  src=w5; dst=wt2+2*512*512;   break;
            case 6: K=512;  M=1024; src=w6; dst=f1t;             break;
            default:K=1024; M=512;  src=w7; dst=f2t;             break;
        }
        const int m0 = blockIdx.x * 32, k0 = blockIdx.y * 32;
        if (m0 >= M || k0 >= K) return;
        __shared__ u16 t[32][33];
        const int tx = tid & 31, ty = tid >> 5;
        #pragma unroll
        for (int i = 0; i < 4; ++i) {
            const int kk = k0 + ty + i * 8;
            t[ty + i * 8][tx] = isf ? ftrunc_bf(((const float*)src)[(size_t)kk * M + m0 + tx])
                                    : ((const u16*)src)[(size_t)kk * M + m0 + tx];
        }
        __syncthreads();
        #pragma unroll
        for (int i = 0; i < 4; ++i) {
            const int mm = m0 + ty + i * 8;
            dst[(size_t)mm * K + k0 + tx] = t[tx][ty + i * 8];
        }
    } else if (z == 8) {
        const int bid = blockIdx.y * 32 + blockIdx.x;    // 0..1023
        const int base = bid * 2048 + tid * 8;
        if (isf) {
            #pragma unroll
            for (int j = 0; j < 8; ++j)
                xbf[base + j] = ftrunc_bf(((const float*)xsrc)[base + j]);
        } else {
            *(u16x8*)&xbf[base] = *(const u16x8*)&xsrc[base];
        }
    } else {
        const int bid = blockIdx.y * 32 + blockIdx.x;
        if (bid >= 28) return;
        const int e = bid * 256 + tid;
        int id, i;
        if (e < 3072)      { id = e >> 9;               i = e & 511;          }
        else if (e < 4096) { id = 6;                    i = e - 3072;         }
        else               { id = 7 + ((e - 4096) >> 9); i = (e - 4096) & 511; }
        const void* src;
        switch (id) {
            case 0: src = p0; break;  case 1: src = p1; break;
            case 2: src = p2; break;  case 3: src = p3; break;
            case 4: src = p4; break;  case 5: src = p5; break;
            case 6: src = p6; break;  case 7: src = p7; break;
            case 8: src = p8; break;  case 9: src = p9; break;
            case 10: src = p10; break; default: src = p11; break;
        }
        small[e] = isf ? ((const float*)src)[i] : bf2f(((const u16*)src)[i]);
    }
}

// ---------------------------------------------------------------------------
// MFMA GEMM: out[N,M] = act(A[N,K] @ Wt[M,K]^T + bias). TRxTC tile, BK=64.
// VOUT: for which==2 (v in gemm2), write transposed [B][H][HD][S] via LDS.
// ---------------------------------------------------------------------------
template <int TR, int TC, bool RELU, bool AWHICH, bool VOUT>
__global__ __launch_bounds__(256) void gemm_bt(
    const u16* __restrict__ Aall, const u16* __restrict__ Wtall,
    const float* __restrict__ ball, u16* __restrict__ out,
    u16* __restrict__ vtb, int N, int K, int M)
{
    constexpr int RT = TR / 32, CT = TC / 32;
    constexpr int AR = TR / 32, BR = TC / 32;
    constexpr int SSTAGE = (TR + TC) * 64;
    constexpr int SELEMS = VOUT ? (SSTAGE > 128 * 136 ? SSTAGE : 128 * 136) : SSTAGE;
    __shared__ __align__(16) u16 smem[SELEMS];
    u16* sA = smem;
    u16* sB = smem + TR * 64;

    const int mtiles = M / TC;
    const int which = blockIdx.x / mtiles;
    const int colb  = blockIdx.x % mtiles;
    const int row0 = blockIdx.y * TR, col0 = colb * TC;
    const u16* A  = Aall + (AWHICH ? (size_t)which * N * K : 0);
    const u16* Wt = Wtall + (size_t)which * M * K;
    const float* bias = ball + (size_t)which * M;

    const int tid = threadIdx.x;
    const int lane = tid & 63, w = tid >> 6;
    const int wrow = (w & 1) * (TR / 2), wcol = (w >> 1) * (TC / 2);
    const int c = lane & 15, quad = lane >> 4;

    const u16* ap[AR]; const u16* bp[BR];
    #pragma unroll
    for (int i = 0; i < AR; ++i) {
        const int raw = i * 256 + tid, r = raw >> 3, ch = (raw & 7) ^ (r & 7);
        ap[i] = A + (size_t)(row0 + r) * K + ch * 8;
    }
    #pragma unroll
    for (int i = 0; i < BR; ++i) {
        const int raw = i * 256 + tid, r = raw >> 3, ch = (raw & 7) ^ (r & 7);
        bp[i] = Wt + (size_t)(col0 + r) * K + ch * 8;
    }

    f32x4 acc[RT][CT] = {};

    for (int k0 = 0; k0 < K; k0 += 64) {
        __syncthreads();
        #pragma unroll
        for (int i = 0; i < AR; ++i) {
            async16(ap[i], (char*)sA + (i * 256 + tid) * 16);
            ap[i] += 64;
        }
        #pragma unroll
        for (int i = 0; i < BR; ++i) {
            async16(bp[i], (char*)sB + (i * 256 + tid) * 16);
            bp[i] += 64;
        }
        __syncthreads();

        #pragma unroll
        for (int kt = 0; kt < 2; ++kt) {
            bf16x8 af[RT], bfr[CT];
            #pragma unroll
            for (int rt = 0; rt < RT; ++rt) {
                const int r = wrow + rt * 16 + c;
                af[rt] = *(const bf16x8*)&sA[(r * 8 + ((kt * 4 + quad) ^ (r & 7))) * 8];
            }
            #pragma unroll
            for (int ct = 0; ct < CT; ++ct) {
                const int r = wcol + ct * 16 + c;
                bfr[ct] = *(const bf16x8*)&sB[(r * 8 + ((kt * 4 + quad) ^ (r & 7))) * 8];
            }
            #pragma unroll
            for (int rt = 0; rt < RT; ++rt)
                #pragma unroll
                for (int ct = 0; ct < CT; ++ct)
                    acc[rt][ct] = mfma16(af[rt], bfr[ct], acc[rt][ct]);
        }
    }

    if (VOUT && which == 2) {
        // transpose through LDS: smem[col][row], pad 136 (16B-aligned rows)
        __syncthreads();
        #pragma unroll
        for (int rt = 0; rt < RT; ++rt) {
            const int rowb = wrow + rt * 16 + quad * 4;
            #pragma unroll
            for (int ct = 0; ct < CT; ++ct) {
                const int col = wcol + ct * 16 + c;
                ushort4 pk;
                pk.x = ftrunc_bf(acc[rt][ct][0] + bias[col0 + col]);
                pk.y = ftrunc_bf(acc[rt][ct][1] + bias[col0 + col]);
                pk.z = ftrunc_bf(acc[rt][ct][2] + bias[col0 + col]);
                pk.w = ftrunc_bf(acc[rt][ct][3] + bias[col0 + col]);
                *(ushort4*)&smem[col * 136 + rowb] = pk;
            }
        }
        __syncthreads();
        const int dl = tid >> 1, half = tid & 1;
        const int hg = (col0 + dl) >> 6, dd = (col0 + dl) & 63;
        const int bb = row0 >> 11, s0 = row0 & 2047;
        u16* dst = vtb + ((size_t)(bb * NH + hg) * HD + dd) * SS + s0 + half * 64;
        #pragma unroll
        for (int j = 0; j < 8; ++j)
            *(u16x8*)&dst[j * 8] = *(const u16x8*)&smem[dl * 136 + half * 64 + j * 8];
        return;
    }

    const size_t outW = (size_t)which * N * M;
    #pragma unroll
    for (int rt = 0; rt < RT; ++rt) {
        #pragma unroll
        for (int i = 0; i < 4; ++i) {
            const int row = row0 + wrow + rt * 16 + quad * 4 + i;
            #pragma unroll
            for (int ct = 0; ct < CT; ++ct) {
                const int col = col0 + wcol + ct * 16 + c;
                float v = acc[rt][ct][i] + bias[col];
                if (RELU) v = fmaxf(v, 0.0f);
                out[outW + (size_t)row * M + col] = ftrunc_bf(v);
            }
        }
    }
}

// ---------------------------------------------------------------------------
// MFMA flash attention. Q-tile 128 (4 waves x 32 queries, 2 Q-frags/wave),
// double-buffered K/V staging, XCD-pinned (b,h), no-max log2 softmax.
// ---------------------------------------------------------------------------
__global__ __launch_bounds__(256) void attn_mfma(
    const u16* __restrict__ q, const u16* __restrict__ k,
    const u16* __restrict__ vt, u16* __restrict__ ctx)
{
    __shared__ __align__(16) u16 sK[2][64 * 64];
    __shared__ __align__(16) u16 sV[2][64 * 64];
    __shared__ __align__(16) u16 sP[4][32 * 64];

    const int tid = threadIdx.x;
    const int w = tid >> 6, lane = tid & 63;
    const int c = lane & 15, quad = lane >> 4;
    // XCD swizzle: id&7 = xcd (round-robin dispatch); 4 (b,h) pairs per XCD
    const int id = blockIdx.x;
    const int slot = id >> 3;
    const int bh = ((id & 7) << 2) | (slot >> 4);
    const int qt = slot & 15;
    const int b = bh >> 3, h = bh & 7;
    const int q0 = qt * 128;
    const size_t tokbase = (size_t)b * SS;
    const int hoff = h * HD;

    bf16x8 qf[2][2];
    #pragma unroll
    for (int f = 0; f < 2; ++f)
        #pragma unroll
        for (int kt = 0; kt < 2; ++kt)
            qf[f][kt] = *(const bf16x8*)&q[(tokbase + q0 + w * 32 + f * 16 + c) * EMB
                                           + hoff + kt * 32 + quad * 8];

    const u16* kp[2]; const u16* vp[2];
    #pragma unroll
    for (int i = 0; i < 2; ++i) {
        const int raw = i * 256 + tid, rr = raw >> 3, ch = (raw & 7) ^ (rr & 7);
        kp[i] = k + (tokbase + rr) * EMB + hoff + ch * 8;
        vp[i] = vt + ((size_t)(b * NH + h) * HD + rr) * SS + ch * 8;
    }
    auto stage = [&](int buf) {
        #pragma unroll
        for (int i = 0; i < 2; ++i) {
            async16(kp[i], (char*)sK[buf] + (i * 256 + tid) * 16);
            kp[i] += 64 * EMB;
        }
        #pragma unroll
        for (int i = 0; i < 2; ++i) {
            async16(vp[i], (char*)sV[buf] + (i * 256 + tid) * 16);
            vp[i] += 64;
        }
    };
    stage(0);

    float l0 = 0.0f, l1 = 0.0f;
    f32x4 accO[2][4] = {};

    for (int t = 0; t < SS / 64; ++t) {
        __syncthreads();                    // drains stage(t) (issued 1 iter ago)
        const int buf = t & 1;
        if (t < SS / 64 - 1) stage(buf ^ 1);

        // S^T[key][q] for both Q-frags; each kf read feeds 2 MFMAs
        f32x4 accS[2][4] = {};
        #pragma unroll
        for (int mt = 0; mt < 4; ++mt) {
            const int key = mt * 16 + c;
            #pragma unroll
            for (int kt = 0; kt < 2; ++kt) {
                bf16x8 kf = *(const bf16x8*)&sK[buf][(key * 8 + ((kt * 4 + quad) ^ (key & 7))) * 8];
                accS[0][mt] = mfma16(kf, qf[0][kt], accS[0][mt]);
                accS[1][mt] = mfma16(kf, qf[1][kt], accS[1][mt]);
            }
        }

        // softmax (no max, log2 domain) + P^T to per-wave LDS
        #pragma unroll
        for (int f = 0; f < 2; ++f) {
            const int row = f * 16 + c;
            float ls = 0.0f;
            u32 pw[8];
            #pragma unroll
            for (int mt = 0; mt < 4; ++mt) {
                const float e0 = __builtin_amdgcn_exp2f(fmaf(accS[f][mt][0], C2, RB));
                const float e1 = __builtin_amdgcn_exp2f(fmaf(accS[f][mt][1], C2, RB));
                const float e2 = __builtin_amdgcn_exp2f(fmaf(accS[f][mt][2], C2, RB));
                const float e3 = __builtin_amdgcn_exp2f(fmaf(accS[f][mt][3], C2, RB));
                ls += (e0 + e1) + (e2 + e3);
                pw[2 * mt]     = __builtin_amdgcn_perm(__float_as_uint(e1), __float_as_uint(e0), 0x07060302u);
                pw[2 * mt + 1] = __builtin_amdgcn_perm(__float_as_uint(e3), __float_as_uint(e2), 0x07060302u);
            }
            if (f == 0) l0 += ls; else l1 += ls;
            #pragma unroll
            for (int mt = 0; mt < 4; ++mt) {
                const int chunk = 2 * mt + (quad >> 1);
                uint2 u; u.x = pw[2 * mt]; u.y = pw[2 * mt + 1];
                *(uint2*)((char*)&sP[w][0] + (row * 8 + (chunk ^ (c & 7))) * 16 + 8 * (quad & 1)) = u;
            }
        }

        // PV: each vf read feeds 2 MFMAs
        bf16x8 pf[2][2];
        #pragma unroll
        for (int f = 0; f < 2; ++f)
            #pragma unroll
            for (int kt = 0; kt < 2; ++kt)
                pf[f][kt] = *(const bf16x8*)&sP[w][((f * 16 + c) * 8 + ((kt * 4 + quad) ^ (c & 7))) * 8];
        #pragma unroll
        for (int nt = 0; nt < 4; ++nt) {
            const int d = nt * 16 + c;
            #pragma unroll
            for (int kt = 0; kt < 2; ++kt) {
                bf16x8 vf = *(const bf16x8*)&sV[buf][(d * 8 + ((kt * 4 + quad) ^ (d & 7))) * 8];
                accO[0][nt] = mfma16(pf[0][kt], vf, accO[0][nt]);
                accO[1][nt] = mfma16(pf[1][kt], vf, accO[1][nt]);
            }
        }
    }

    #pragma unroll
    for (int f = 0; f < 2; ++f) {
        float l = (f == 0) ? l0 : l1;
        l += __shfl_xor(l, 16);
        l += __shfl_xor(l, 32);
        float li[4];
        #pragma unroll
        for (int i = 0; i < 4; ++i) {
            const float lv = __shfl(l, quad * 4 + i, 16);
            li[i] = (lv > 0.0f) ? (1.0f / lv) : 0.0f;
        }
        #pragma unroll
        for (int nt = 0; nt < 4; ++nt)
            #pragma unroll
            for (int i = 0; i < 4; ++i) {
                const int tok = q0 + w * 32 + f * 16 + quad * 4 + i;
                ctx[(tokbase + tok) * EMB + hoff + nt * 16 + c] =
                    ftrunc_bf(accO[f][nt][i] * li[i]);
            }
    }
}

// ---------------------------------------------------------------------------
// Residual + LayerNorm over EMB=512, bf16 in, one wave per row.
// ---------------------------------------------------------------------------
__global__ __launch_bounds__(256) void ln_mid(
    const u16* __restrict__ a, const u16* __restrict__ b2,
    const float* __restrict__ g, const float* __restrict__ be,
    u16* __restrict__ outb)
{
    const int wave = threadIdx.x >> 6, lane = threadIdx.x & 63;
    const size_t row = (size_t)blockIdx.x * 4 + wave;
    const u16x8 av = *(const u16x8*)&a[row * EMB + lane * 8];
    const u16x8 bv = *(const u16x8*)&b2[row * EMB + lane * 8];
    float vals[8], sum = 0.0f;
    #pragma unroll
    for (int i = 0; i < 8; ++i) { vals[i] = bf2f(av[i]) + bf2f(bv[i]); sum += vals[i]; }
    #pragma unroll
    for (int o = 1; o < 64; o <<= 1) sum += __shfl_xor(sum, o);
    const float mu = sum * (1.0f / 512.0f);
    float vs = 0.0f;
    #pragma unroll
    for (int i = 0; i < 8; ++i) { const float d = vals[i] - mu; vs += d * d; }
    #pragma unroll
    for (int o = 1; o < 64; o <<= 1) vs += __shfl_xor(vs, o);
    const float rstd = rsqrtf(vs * (1.0f / 512.0f) + EPS);
    u16x8 ov;
    #pragma unroll
    for (int i = 0; i < 8; ++i) {
        const int col = lane * 8 + i;
        ov[i] = f2bf((vals[i] - mu) * rstd * g[col] + be[col]);
    }
    *(u16x8*)&outb[row * EMB + lane * 8] = ov;
}

__global__ __launch_bounds__(256) void ln_final(
    const u16* __restrict__ a, const u16* __restrict__ b2,
    const float* __restrict__ g, const float* __restrict__ be,
    void* __restrict__ dout, const u16* __restrict__ xsrc)
{
    const int isf = derive_flag(xsrc);
    const int wave = threadIdx.x >> 6, lane = threadIdx.x & 63;
    const size_t row = (size_t)blockIdx.x * 4 + wave;
    const u16x8 av = *(const u16x8*)&a[row * EMB + lane * 8];
    const u16x8 bv = *(const u16x8*)&b2[row * EMB + lane * 8];
    float vals[8], sum = 0.0f;
    #pragma unroll
    for (int i = 0; i < 8; ++i) { vals[i] = bf2f(av[i]) + bf2f(bv[i]); sum += vals[i]; }
    #pragma unroll
    for (int o = 1; o < 64; o <<= 1) sum += __shfl_xor(sum, o);
    const float mu = sum * (1.0f / 512.0f);
    float vs = 0.0f;
    #pragma unroll
    for (int i = 0; i < 8; ++i) { const float d = vals[i] - mu; vs += d * d; }
    #pragma unroll
    for (int o = 1; o < 64; o <<= 1) vs += __shfl_xor(vs, o);
    const float rstd = rsqrtf(vs * (1.0f / 512.0f) + EPS);
    if (isf) {
        #pragma unroll
        for (int i = 0; i < 8; ++i) {
            const int col = lane * 8 + i;
            ((float*)dout)[row * EMB + col] = (vals[i] - mu) * rstd * g[col] + be[col];
        }
    } else {
        u16x8 ov;
        #pragma unroll
        for (int i = 0; i < 8; ++i) {
            const int col = lane * 8 + i;
            ov[i] = f2bf((vals[i] - mu) * rstd * g[col] + be[col]);
        }
        *(u16x8*)&((u16*)dout)[row * EMB + lane * 8] = ov;
    }
}

// ---------------------------------------------------------------------------
extern "C" void kernel_launch(void* const* d_in, const int* in_sizes, int n_in,
                              void* d_out, int out_size, void* d_ws, size_t ws_size,
                              hipStream_t stream)
{
    char* ws = (char*)d_ws;
    float* small = (float*)(ws + 0);        // 7168 f32
    u16*   wt1   = (u16*)(ws + 32768);
    u16*   wt2   = (u16*)(ws + 819200);
    u16*   f1t   = (u16*)(ws + 2392064);
    u16*   f2t   = (u16*)(ws + 3440640);
    u16*   xbf   = (u16*)(ws + 4489216);
    u16*   h3    = (u16*)(ws + 8683520);    // [3][NT][512]; reused as h2 [NT][1024]
    u16*   qkv   = (u16*)(ws + 33849344);   // [3][NT][512] (v slot unused)
    u16*   vtb   = (u16*)(ws + 59015168);   // [B][H][64][S]
    u16*   ctxb  = (u16*)(ws + 67403776);
    u16*   x1b   = (u16*)(ws + 75792384);
    u16*   ffb   = (u16*)(ws + 84180992);

    const dim3 blk(256);
    const u16* xsrc = (const u16*)d_in[0];

    prep<<<dim3(32, 32, 10), blk, 0, stream>>>(
        xsrc,
        d_in[1], d_in[5], d_in[9], d_in[3], d_in[7], d_in[11], d_in[13], d_in[15],
        d_in[2], d_in[6], d_in[10], d_in[4], d_in[8], d_in[12],
        d_in[14], d_in[16], d_in[17], d_in[18], d_in[19], d_in[20],
        xbf, wt1, wt2, f1t, f2t, small);

    // qkv layer 1: h3[which] = relu(x @ W1 + b1)
    gemm_bt<128, 128, true, false, false><<<dim3(12, 64), blk, 0, stream>>>(
        xbf, wt1, small + 0, h3, nullptr, NT, INF_, EMB);
    // qkv layer 2: q,k -> qkv; v -> vtb (transposed epilogue)
    gemm_bt<128, 128, false, true, true><<<dim3(12, 64), blk, 0, stream>>>(
        h3, wt2, small + 1536, qkv, vtb, NT, EMB, EMB);

    attn_mfma<<<dim3(512), blk, 0, stream>>>(
        qkv, qkv + (size_t)NT * EMB, vtb, ctxb);

    // x1 = LN(ctx + q)
    ln_mid<<<NT / 4, blk, 0, stream>>>(ctxb, qkv, small + 4608, small + 5120, x1b);

    // FFN
    u16* h2 = h3;
    gemm_bt<128, 128, true, false, false><<<dim3(8, 64), blk, 0, stream>>>(
        x1b, f1t, small + 3072, h2, nullptr, NT, EMB, 1024);
    gemm_bt<128, 64, false, false, false><<<dim3(8, 64), blk, 0, stream>>>(
        h2, f2t, small + 4096, ffb, nullptr, NT, 1024, EMB);

    // out = LN(x1 + ff)
    ln_final<<<NT / 4, blk, 0, stream>>>(x1b, ffb, small + 5632, small + 6144, d_out, xsrc);
}